// Round 4
// baseline (205.965 us; speedup 1.0000x reference)
//
#include <hip/hip_runtime.h>
#include <hip/hip_bf16.h>
#include <math.h>

#define NN 4096
#define DD 127
#define HH 128
#define OUTD 3
#define NTYPES 6
#define SIM_THRESH 0.9f
#define BN_EPS 1e-5f
#define MROW 4   // rows per block in build_mask: amortizes fn reads 4x
#define LRPB 4   // rows per block in layer_kernel (one wave per row)
#define LMAX 2560 // per-row neighbor list capacity (mean ~170; 15x headroom)

// ---------------------------------------------------------------------------
// Kernel H: per-type histogram, shuffle-reduced (96 global atomics total).
// ---------------------------------------------------------------------------
__global__ __launch_bounds__(256) void type_hist(
    const int* __restrict__ sat, int* __restrict__ cnt)
{
    int gid = blockIdx.x * 256 + threadIdx.x;
    int lane = threadIdx.x & 63;
    int cc[NTYPES] = {0, 0, 0, 0, 0, 0};
    for (int i = gid; i < NN; i += 4 * 256) {
        int s = sat[i]; s = min(max(s, 0), NTYPES - 1);
        #pragma unroll
        for (int t = 0; t < NTYPES; ++t) cc[t] += (s == t);
    }
    #pragma unroll
    for (int t = 0; t < NTYPES; ++t) {
        int v = cc[t];
        for (int s = 32; s; s >>= 1) v += __shfl_down(v, s);
        if (lane == 0 && v) atomicAdd(&cnt[t], v);
    }
}

// ---------------------------------------------------------------------------
// Kernel A: x = concat(x_now[:, :1], x_now) and fn[i]=normalize([x0,x0,x1,x2])
// ---------------------------------------------------------------------------
__global__ __launch_bounds__(HH) void build_x_fn(
    const float* __restrict__ x_now,
    float* __restrict__ x, float4* __restrict__ fn)
{
    int i = blockIdx.x;
    int k = threadIdx.x;
    const float* row = x_now + (size_t)i * DD;
    float v = (k == 0) ? row[0] : row[k - 1];
    x[(size_t)i * HH + k] = v;
    if (k == 0) {
        float f0 = row[0], f2 = row[1], f3 = row[2];
        float nrm = sqrtf(2.f * f0 * f0 + f2 * f2 + f3 * f3);
        nrm = fmaxf(nrm, 1e-12f);
        float inv = 1.f / nrm;
        fn[i] = make_float4(f0 * inv, f0 * inv, f2 * inv, f3 * inv);
    }
}

// ---------------------------------------------------------------------------
// Kernel B: cross-type cosine adjacency bitmask + degree, MROW rows/block.
// Bit layout: word w (0..127) of row i, bit b (0..31) <-> j = b*128 + w.
// ---------------------------------------------------------------------------
__global__ __launch_bounds__(HH) void build_mask(
    const float4* __restrict__ fn, const int* __restrict__ sat,
    const int* __restrict__ cnt, unsigned* __restrict__ mask,
    float* __restrict__ deg)
{
    int i0 = blockIdx.x * MROW;
    int w = threadIdx.x;  // 0..127
    float4 fi[MROW];
    int ti[MROW];
    #pragma unroll
    for (int r = 0; r < MROW; ++r) {
        fi[r] = fn[i0 + r];
        int t = sat[i0 + r];
        ti[r] = min(max(t, 0), NTYPES - 1);
    }
    unsigned word[MROW] = {0, 0, 0, 0};
    for (int b = 0; b < 32; ++b) {
        int j = b * 128 + w;
        float4 fj = fn[j];
        int tj = sat[j];
        #pragma unroll
        for (int r = 0; r < MROW; ++r) {
            float dot = fi[r].x * fj.x + fi[r].y * fj.y
                      + fi[r].z * fj.z + fi[r].w * fj.w;
            if (tj != ti[r] && dot > SIM_THRESH) word[r] |= (1u << b);
        }
    }
    int pcs[MROW];
    #pragma unroll
    for (int r = 0; r < MROW; ++r) {
        mask[(size_t)(i0 + r) * 128 + w] = word[r];
        pcs[r] = __popc(word[r]);
    }
    int lane = w & 63, wv = w >> 6;
    for (int s = 32; s; s >>= 1) {
        #pragma unroll
        for (int r = 0; r < MROW; ++r) pcs[r] += __shfl_down(pcs[r], s);
    }
    __shared__ int wt[2][MROW];
    if (lane == 0) {
        #pragma unroll
        for (int r = 0; r < MROW; ++r) wt[wv][r] = pcs[r];
    }
    __syncthreads();
    if (w < MROW) {
        int r = w;
        int tt = sat[i0 + r]; tt = min(max(tt, 0), NTYPES - 1);
        float d = (float)(cnt[tt] - 1 + wt[0][r] + wt[1][r]);
        deg[i0 + r] = fmaxf(d, 1.0f);
    }
}

// ---------------------------------------------------------------------------
// Kernel C: per-type column sums S[t][k] = sum_{i: type(i)=t} h[i][k]
// ---------------------------------------------------------------------------
__global__ __launch_bounds__(HH) void type_sums(
    const float* __restrict__ h, const int* __restrict__ sat,
    float* __restrict__ S)
{
    int k = threadIdx.x;
    int base = blockIdx.x * 128;
    __shared__ float ls[NTYPES][HH];
    for (int t = 0; t < NTYPES; ++t) ls[t][k] = 0.f;
    for (int r = 0; r < 128; ++r) {
        int i = base + r;
        int t = sat[i]; t = min(max(t, 0), NTYPES - 1);
        ls[t][k] += h[(size_t)i * HH + k];
    }
    for (int t = 0; t < NTYPES; ++t) atomicAdd(&S[t * HH + k], ls[t][k]);
}

// ---------------------------------------------------------------------------
// Kernel D v3: one WAVE per row (4 waves = 4 rows per 256-thread block).
// Per wave: decode bitmask -> private LDS CSR list (shfl scan, no barrier);
// gather 2 neighbor-slots x 32 float4 chunks, 4-deep ILP; cross-half
// shfl reduce; compute m into LDS. ONE barrier, then matmul phase with W
// rows per thread, each thread covering 2 rows (o = t&127).
// ---------------------------------------------------------------------------
__global__ __launch_bounds__(256) void layer_kernel(
    const float* __restrict__ h, const unsigned* __restrict__ mask,
    const float* __restrict__ deg, const float* __restrict__ S,
    const int* __restrict__ sat,
    const float* __restrict__ Wl, const float* __restrict__ bl,
    const float* __restrict__ Wr, float* __restrict__ hout)
{
    int t = threadIdx.x;
    int wv = t >> 6;          // wave id = row slot 0..3
    int lane = t & 63;
    int i0 = blockIdx.x * LRPB;
    int i = i0 + wv;

    __shared__ unsigned short list[LRPB][LMAX];          // 20 KB
    __shared__ __align__(16) float hs[LRPB][HH];         // 2 KB
    __shared__ __align__(16) float ms[LRPB][HH];         // 2 KB

    // ---- decode: each lane owns mask words lane and lane+64 ----
    const unsigned* mrow = mask + (size_t)i * 128;
    unsigned w0 = mrow[lane];
    unsigned w1 = mrow[lane + 64];
    int pc = __popc(w0) + __popc(w1);
    int x = pc;
    for (int s = 1; s < 64; s <<= 1) {
        int v = __shfl_up(x, s);
        if (lane >= s) x += v;
    }
    int ncnt = __shfl(x, 63);
    int ofs = x - pc;
    unsigned ww = w0;
    while (ww) {
        int b = __ffs(ww) - 1; ww &= ww - 1;
        list[wv][ofs++] = (unsigned short)(b * 128 + lane);
    }
    ww = w1;
    while (ww) {
        int b = __ffs(ww) - 1; ww &= ww - 1;
        list[wv][ofs++] = (unsigned short)(b * 128 + lane + 64);
    }
    // own row into LDS (float2 per lane)
    ((float2*)hs[wv])[lane] = ((const float2*)(h + (size_t)i * HH))[lane];

    // ---- gather: q = neighbor slot (0/1), c = float4 chunk (0..31) ----
    int q = lane >> 5;
    int c = lane & 31;
    const float4* __restrict__ h4 = (const float4*)h;
    float4 a0 = {0,0,0,0}, a1 = {0,0,0,0}, a2 = {0,0,0,0}, a3 = {0,0,0,0};
    int g = 0;
    for (; g + 8 <= ncnt; g += 8) {
        int j0 = list[wv][g + q];
        int j1 = list[wv][g + 2 + q];
        int j2 = list[wv][g + 4 + q];
        int j3 = list[wv][g + 6 + q];
        float4 v0 = h4[j0 * 32 + c];
        float4 v1 = h4[j1 * 32 + c];
        float4 v2 = h4[j2 * 32 + c];
        float4 v3 = h4[j3 * 32 + c];
        a0.x += v0.x; a0.y += v0.y; a0.z += v0.z; a0.w += v0.w;
        a1.x += v1.x; a1.y += v1.y; a1.z += v1.z; a1.w += v1.w;
        a2.x += v2.x; a2.y += v2.y; a2.z += v2.z; a2.w += v2.w;
        a3.x += v3.x; a3.y += v3.y; a3.z += v3.z; a3.w += v3.w;
    }
    for (; g + 2 <= ncnt; g += 2) {
        int j0 = list[wv][g + q];
        float4 v0 = h4[j0 * 32 + c];
        a0.x += v0.x; a0.y += v0.y; a0.z += v0.z; a0.w += v0.w;
    }
    if (q < ncnt - g) {
        int j0 = list[wv][g + q];
        float4 v0 = h4[j0 * 32 + c];
        a1.x += v0.x; a1.y += v0.y; a1.z += v0.z; a1.w += v0.w;
    }
    float4 tt;
    tt.x = a0.x + a1.x + a2.x + a3.x;
    tt.y = a0.y + a1.y + a2.y + a3.y;
    tt.z = a0.z + a1.z + a2.z + a3.z;
    tt.w = a0.w + a1.w + a2.w + a3.w;
    // fold slot 1 into slot 0 (lanes 0..31)
    tt.x += __shfl_down(tt.x, 32);
    tt.y += __shfl_down(tt.y, 32);
    tt.z += __shfl_down(tt.z, 32);
    tt.w += __shfl_down(tt.w, 32);
    if (q == 0) {
        int ti = sat[i]; ti = min(max(ti, 0), NTYPES - 1);
        float rdeg = 1.f / deg[i];
        float4 hv = ((const float4*)hs[wv])[c];
        float4 Sv = ((const float4*)S)[ti * 32 + c];
        float4 m;
        m.x = (Sv.x - hv.x + tt.x) * rdeg;
        m.y = (Sv.y - hv.y + tt.y) * rdeg;
        m.z = (Sv.z - hv.z + tt.z) * rdeg;
        m.w = (Sv.w - hv.w + tt.w) * rdeg;
        ((float4*)ms[wv])[c] = m;
    }
    __syncthreads();   // the ONLY block-wide barrier

    // ---- matmul: o = t&127, half-block covers 2 rows ----
    int o = t & 127;
    int pr = (t >> 7) * 2;   // 0 or 2
    const float4* __restrict__ Wl4 = (const float4*)Wl + o * 32;
    const float4* __restrict__ Wr4 = (const float4*)Wr + o * 32;
    float bias = bl[o];
    float acc0 = bias, acc1 = bias;
    for (int qq = 0; qq < 32; ++qq) {
        float4 wa = Wl4[qq];
        float4 wb = Wr4[qq];
        float4 m0 = ((const float4*)ms[pr])[qq];
        float4 h0 = ((const float4*)hs[pr])[qq];
        float4 m1 = ((const float4*)ms[pr + 1])[qq];
        float4 h1 = ((const float4*)hs[pr + 1])[qq];
        acc0 += m0.x * wa.x + m0.y * wa.y + m0.z * wa.z + m0.w * wa.w
              + h0.x * wb.x + h0.y * wb.y + h0.z * wb.z + h0.w * wb.w;
        acc1 += m1.x * wa.x + m1.y * wa.y + m1.z * wa.z + m1.w * wa.w
              + h1.x * wb.x + h1.y * wb.y + h1.z * wb.z + h1.w * wb.w;
    }
    hout[(size_t)(i0 + pr) * HH + o]     = fmaxf(acc0, 0.f);
    hout[(size_t)(i0 + pr + 1) * HH + o] = fmaxf(acc1, 0.f);
}

// ---------------------------------------------------------------------------
// Kernel E: batchnorm stats (sum, sumsq per column)
// ---------------------------------------------------------------------------
__global__ __launch_bounds__(HH) void bn_stats(
    const float* __restrict__ h, float* __restrict__ musum,
    float* __restrict__ varsum)
{
    int k = threadIdx.x;
    int base = blockIdx.x * 128;
    float s = 0.f, s2 = 0.f;
    for (int r = 0; r < 128; ++r) {
        float v = h[(size_t)(base + r) * HH + k];
        s += v; s2 += v * v;
    }
    atomicAdd(&musum[k], s);
    atomicAdd(&varsum[k], s2);
}

// ---------------------------------------------------------------------------
// Kernel F v3: BN apply + head, one wave per row, zero barriers.
// Lane owns column pair (2k, 2k+1); head dot via shfl reduce.
// ---------------------------------------------------------------------------
__global__ __launch_bounds__(256) void finalize(
    const float* __restrict__ h, const float* __restrict__ musum,
    const float* __restrict__ varsum, const float* __restrict__ gamma,
    const float* __restrict__ beta, const float* __restrict__ Wo,
    const float* __restrict__ bo, float* __restrict__ out_h,
    float* __restrict__ out_o)
{
    int t = threadIdx.x;
    int wv = t >> 6;
    int lane = t & 63;
    int i = blockIdx.x * 4 + wv;

    float2 mus = ((const float2*)musum)[lane];
    float2 vas = ((const float2*)varsum)[lane];
    float2 ga  = ((const float2*)gamma)[lane];
    float2 be  = ((const float2*)beta)[lane];
    float mu0 = mus.x * (1.f / NN), mu1 = mus.y * (1.f / NN);
    float v0 = vas.x * (1.f / NN) - mu0 * mu0;
    float v1 = vas.y * (1.f / NN) - mu1 * mu1;
    float sc0 = ga.x / sqrtf(v0 + BN_EPS), sc1 = ga.y / sqrtf(v1 + BN_EPS);
    float sh0 = be.x - mu0 * sc0, sh1 = be.y - mu1 * sc1;

    float2 hv = ((const float2*)(h + (size_t)i * HH))[lane];
    float2 hb;
    hb.x = hv.x * sc0 + sh0;
    hb.y = hv.y * sc1 + sh1;
    ((float2*)(out_h + (size_t)i * HH))[lane] = hb;

    float2 w0 = ((const float2*)Wo)[lane];
    float2 w1 = ((const float2*)(Wo + HH))[lane];
    float2 w2 = ((const float2*)(Wo + 2 * HH))[lane];
    float p0 = hb.x * w0.x + hb.y * w0.y;
    float p1 = hb.x * w1.x + hb.y * w1.y;
    float p2 = hb.x * w2.x + hb.y * w2.y;
    for (int s = 32; s; s >>= 1) {
        p0 += __shfl_down(p0, s);
        p1 += __shfl_down(p1, s);
        p2 += __shfl_down(p2, s);
    }
    if (lane == 0) {
        out_o[(size_t)i * OUTD + 0] = p0 + bo[0];
        out_o[(size_t)i * OUTD + 1] = p1 + bo[1];
        out_o[(size_t)i * OUTD + 2] = p2 + bo[2];
    }
}

// ---------------------------------------------------------------------------
extern "C" void kernel_launch(void* const* d_in, const int* in_sizes, int n_in,
                              void* d_out, int out_size, void* d_ws, size_t ws_size,
                              hipStream_t stream)
{
    (void)in_sizes; (void)n_in; (void)out_size; (void)ws_size;
    const float* x_now = (const float*)d_in[0];
    const int*   sat   = (const int*)d_in[1];
    const float* Wl    = (const float*)d_in[2];
    const float* bl    = (const float*)d_in[3];
    const float* Wr    = (const float*)d_in[4];
    const float* gamma = (const float*)d_in[5];
    const float* beta  = (const float*)d_in[6];
    const float* Wo    = (const float*)d_in[7];
    const float* bo    = (const float*)d_in[8];

    float* ws = (float*)d_ws;
    float* x0 = ws;                          // 524288 floats
    float* h1 = x0 + (size_t)NN * HH;        // 524288
    float* h2 = h1 + (size_t)NN * HH;        // 524288
    float4* fn = (float4*)(h2 + (size_t)NN * HH);      // 4096 float4
    unsigned* mask = (unsigned*)((float*)fn + 4 * NN); // 524288 words
    float* deg = (float*)(mask + (size_t)NN * 128);    // 4096
    int* cnt = (int*)(deg + NN);             // 8 ints
    float* S0 = (float*)(cnt + 8);           // 768
    float* S1 = S0 + NTYPES * HH;            // 768
    float* musum = S1 + NTYPES * HH;         // 128
    float* varsum = musum + HH;              // 128

    size_t zero_bytes = (8 + 2 * NTYPES * HH + 2 * HH) * sizeof(float);
    hipMemsetAsync(cnt, 0, zero_bytes, stream);

    type_hist<<<4, 256, 0, stream>>>(sat, cnt);
    build_x_fn<<<NN, HH, 0, stream>>>(x_now, x0, fn);
    build_mask<<<NN / MROW, HH, 0, stream>>>(fn, sat, cnt, mask, deg);

    type_sums<<<32, HH, 0, stream>>>(x0, sat, S0);
    layer_kernel<<<NN / LRPB, 256, 0, stream>>>(x0, mask, deg, S0, sat,
                                                Wl, bl, Wr, h1);
    type_sums<<<32, HH, 0, stream>>>(h1, sat, S1);
    layer_kernel<<<NN / LRPB, 256, 0, stream>>>(h1, mask, deg, S1, sat,
                                                Wl + 16384, bl + HH, Wr + 16384, h2);

    bn_stats<<<32, HH, 0, stream>>>(h2, musum, varsum);
    finalize<<<NN / 4, 256, 0, stream>>>(h2, musum, varsum, gamma, beta, Wo, bo,
                                         (float*)d_out, (float*)d_out + (size_t)NN * HH);
}

// Round 5
// 185.365 us; speedup vs baseline: 1.1111x; 1.1111x over previous
//
#include <hip/hip_runtime.h>
#include <hip/hip_bf16.h>
#include <math.h>

#define NN 4096
#define DD 127
#define HH 128
#define OUTD 3
#define NTYPES 6
#define SIM_THRESH 0.9f
#define BN_EPS 1e-5f
#define MROW 4    // rows per block in build_mask: amortizes fn reads 4x
#define LRPB 4    // rows per block in layer_kernel (one wave per row)
#define LMAX 2560 // per-row neighbor list capacity (mean ~170; 15x headroom)

// ---------------------------------------------------------------------------
// Kernel T: transpose the 4 weight matrices (Wl0,Wl1,Wr0,Wr1) into WT[k][o]
// so layer_kernel's matmul reads W coalesced. LDS-tile transpose, pad 129
// floats/row -> bank stride 1 on the strided read side. Runs once, 4 blocks.
// ---------------------------------------------------------------------------
__global__ __launch_bounds__(256) void transpose_w(
    const float* __restrict__ Wl, const float* __restrict__ Wr,
    float* __restrict__ WT)
{
    int m = blockIdx.x;            // 0:Wl0 1:Wl1 2:Wr0 3:Wr1
    const float* src = (m < 2) ? (Wl + m * 16384) : (Wr + (m - 2) * 16384);
    float* dst = WT + m * 16384;
    __shared__ float lds[128 * 129];   // 66 KB; 1 block/CU is fine
    int t = threadIdx.x;
    for (int it = 0; it < 64; ++it) {
        int lin = it * 256 + t;
        int o = lin >> 7, k = lin & 127;
        lds[o * 129 + k] = src[lin];       // global coalesced, LDS seq banks
    }
    __syncthreads();
    for (int it = 0; it < 64; ++it) {
        int lin = it * 256 + t;
        int k = lin >> 7, o = lin & 127;
        dst[lin] = lds[o * 129 + k];       // LDS stride 129 -> bank stride 1
    }
}

// ---------------------------------------------------------------------------
// Kernel H: per-type histogram, shuffle-reduced (96 global atomics total).
// ---------------------------------------------------------------------------
__global__ __launch_bounds__(256) void type_hist(
    const int* __restrict__ sat, int* __restrict__ cnt)
{
    int gid = blockIdx.x * 256 + threadIdx.x;
    int lane = threadIdx.x & 63;
    int cc[NTYPES] = {0, 0, 0, 0, 0, 0};
    for (int i = gid; i < NN; i += 4 * 256) {
        int s = sat[i]; s = min(max(s, 0), NTYPES - 1);
        #pragma unroll
        for (int t = 0; t < NTYPES; ++t) cc[t] += (s == t);
    }
    #pragma unroll
    for (int t = 0; t < NTYPES; ++t) {
        int v = cc[t];
        for (int s = 32; s; s >>= 1) v += __shfl_down(v, s);
        if (lane == 0 && v) atomicAdd(&cnt[t], v);
    }
}

// ---------------------------------------------------------------------------
// Kernel A: x = concat(x_now[:, :1], x_now) and fn[i]=normalize([x0,x0,x1,x2])
// ---------------------------------------------------------------------------
__global__ __launch_bounds__(HH) void build_x_fn(
    const float* __restrict__ x_now,
    float* __restrict__ x, float4* __restrict__ fn)
{
    int i = blockIdx.x;
    int k = threadIdx.x;
    const float* row = x_now + (size_t)i * DD;
    float v = (k == 0) ? row[0] : row[k - 1];
    x[(size_t)i * HH + k] = v;
    if (k == 0) {
        float f0 = row[0], f2 = row[1], f3 = row[2];
        float nrm = sqrtf(2.f * f0 * f0 + f2 * f2 + f3 * f3);
        nrm = fmaxf(nrm, 1e-12f);
        float inv = 1.f / nrm;
        fn[i] = make_float4(f0 * inv, f0 * inv, f2 * inv, f3 * inv);
    }
}

// ---------------------------------------------------------------------------
// Kernel B: cross-type cosine adjacency bitmask + degree, MROW rows/block.
// Bit layout: word w (0..127) of row i, bit b (0..31) <-> j = b*128 + w.
// ---------------------------------------------------------------------------
__global__ __launch_bounds__(HH) void build_mask(
    const float4* __restrict__ fn, const int* __restrict__ sat,
    const int* __restrict__ cnt, unsigned* __restrict__ mask,
    float* __restrict__ deg)
{
    int i0 = blockIdx.x * MROW;
    int w = threadIdx.x;  // 0..127
    float4 fi[MROW];
    int ti[MROW];
    #pragma unroll
    for (int r = 0; r < MROW; ++r) {
        fi[r] = fn[i0 + r];
        int t = sat[i0 + r];
        ti[r] = min(max(t, 0), NTYPES - 1);
    }
    unsigned word[MROW] = {0, 0, 0, 0};
    for (int b = 0; b < 32; ++b) {
        int j = b * 128 + w;
        float4 fj = fn[j];
        int tj = sat[j];
        #pragma unroll
        for (int r = 0; r < MROW; ++r) {
            float dot = fi[r].x * fj.x + fi[r].y * fj.y
                      + fi[r].z * fj.z + fi[r].w * fj.w;
            if (tj != ti[r] && dot > SIM_THRESH) word[r] |= (1u << b);
        }
    }
    int pcs[MROW];
    #pragma unroll
    for (int r = 0; r < MROW; ++r) {
        mask[(size_t)(i0 + r) * 128 + w] = word[r];
        pcs[r] = __popc(word[r]);
    }
    int lane = w & 63, wv = w >> 6;
    for (int s = 32; s; s >>= 1) {
        #pragma unroll
        for (int r = 0; r < MROW; ++r) pcs[r] += __shfl_down(pcs[r], s);
    }
    __shared__ int wt[2][MROW];
    if (lane == 0) {
        #pragma unroll
        for (int r = 0; r < MROW; ++r) wt[wv][r] = pcs[r];
    }
    __syncthreads();
    if (w < MROW) {
        int r = w;
        int tt = sat[i0 + r]; tt = min(max(tt, 0), NTYPES - 1);
        float d = (float)(cnt[tt] - 1 + wt[0][r] + wt[1][r]);
        deg[i0 + r] = fmaxf(d, 1.0f);
    }
}

// ---------------------------------------------------------------------------
// Kernel C: per-type column sums S[t][k] = sum_{i: type(i)=t} h[i][k]
// ---------------------------------------------------------------------------
__global__ __launch_bounds__(HH) void type_sums(
    const float* __restrict__ h, const int* __restrict__ sat,
    float* __restrict__ S)
{
    int k = threadIdx.x;
    int base = blockIdx.x * 128;
    __shared__ float ls[NTYPES][HH];
    for (int t = 0; t < NTYPES; ++t) ls[t][k] = 0.f;
    for (int r = 0; r < 128; ++r) {
        int i = base + r;
        int t = sat[i]; t = min(max(t, 0), NTYPES - 1);
        ls[t][k] += h[(size_t)i * HH + k];
    }
    for (int t = 0; t < NTYPES; ++t) atomicAdd(&S[t * HH + k], ls[t][k]);
}

// ---------------------------------------------------------------------------
// Kernel D v4: one WAVE per row; matmul reads TRANSPOSED W (WT[k][o]) so
// every W load is a contiguous 512B wave segment (was: 64 scattered lines
// per instruction -> ~27us/CU of address-unit serialization, R4 counters).
// k-half split inside the wave, folded by shfl_down(32) — no extra barrier.
// ---------------------------------------------------------------------------
__global__ __launch_bounds__(256) void layer_kernel(
    const float* __restrict__ h, const unsigned* __restrict__ mask,
    const float* __restrict__ deg, const float* __restrict__ S,
    const int* __restrict__ sat,
    const float* __restrict__ WTl, const float* __restrict__ bl,
    const float* __restrict__ WTr, float* __restrict__ hout)
{
    int t = threadIdx.x;
    int wv = t >> 6;          // wave id = row slot 0..3
    int lane = t & 63;
    int i0 = blockIdx.x * LRPB;
    int i = i0 + wv;

    __shared__ unsigned short list[LRPB][LMAX];          // 20 KB
    __shared__ __align__(16) float hs[LRPB][HH];         // 2 KB
    __shared__ __align__(16) float ms[LRPB][HH];         // 2 KB

    // ---- decode: each lane owns mask words lane and lane+64 ----
    const unsigned* mrow = mask + (size_t)i * 128;
    unsigned w0 = mrow[lane];
    unsigned w1 = mrow[lane + 64];
    int pc = __popc(w0) + __popc(w1);
    int x = pc;
    for (int s = 1; s < 64; s <<= 1) {
        int v = __shfl_up(x, s);
        if (lane >= s) x += v;
    }
    int ncnt = __shfl(x, 63);
    int ofs = x - pc;
    unsigned ww = w0;
    while (ww) {
        int b = __ffs(ww) - 1; ww &= ww - 1;
        list[wv][ofs++] = (unsigned short)(b * 128 + lane);
    }
    ww = w1;
    while (ww) {
        int b = __ffs(ww) - 1; ww &= ww - 1;
        list[wv][ofs++] = (unsigned short)(b * 128 + lane + 64);
    }
    ((float2*)hs[wv])[lane] = ((const float2*)(h + (size_t)i * HH))[lane];

    // ---- gather: q = neighbor slot (0/1), c = float4 chunk (0..31) ----
    int q = lane >> 5;
    int c = lane & 31;
    const float4* __restrict__ h4 = (const float4*)h;
    float4 a0 = {0,0,0,0}, a1 = {0,0,0,0}, a2 = {0,0,0,0}, a3 = {0,0,0,0};
    int g = 0;
    for (; g + 8 <= ncnt; g += 8) {
        int j0 = list[wv][g + q];
        int j1 = list[wv][g + 2 + q];
        int j2 = list[wv][g + 4 + q];
        int j3 = list[wv][g + 6 + q];
        float4 v0 = h4[j0 * 32 + c];
        float4 v1 = h4[j1 * 32 + c];
        float4 v2 = h4[j2 * 32 + c];
        float4 v3 = h4[j3 * 32 + c];
        a0.x += v0.x; a0.y += v0.y; a0.z += v0.z; a0.w += v0.w;
        a1.x += v1.x; a1.y += v1.y; a1.z += v1.z; a1.w += v1.w;
        a2.x += v2.x; a2.y += v2.y; a2.z += v2.z; a2.w += v2.w;
        a3.x += v3.x; a3.y += v3.y; a3.z += v3.z; a3.w += v3.w;
    }
    for (; g + 2 <= ncnt; g += 2) {
        int j0 = list[wv][g + q];
        float4 v0 = h4[j0 * 32 + c];
        a0.x += v0.x; a0.y += v0.y; a0.z += v0.z; a0.w += v0.w;
    }
    if (q < ncnt - g) {
        int j0 = list[wv][g + q];
        float4 v0 = h4[j0 * 32 + c];
        a1.x += v0.x; a1.y += v0.y; a1.z += v0.z; a1.w += v0.w;
    }
    float4 tt;
    tt.x = a0.x + a1.x + a2.x + a3.x;
    tt.y = a0.y + a1.y + a2.y + a3.y;
    tt.z = a0.z + a1.z + a2.z + a3.z;
    tt.w = a0.w + a1.w + a2.w + a3.w;
    tt.x += __shfl_down(tt.x, 32);
    tt.y += __shfl_down(tt.y, 32);
    tt.z += __shfl_down(tt.z, 32);
    tt.w += __shfl_down(tt.w, 32);
    if (q == 0) {
        int ti = sat[i]; ti = min(max(ti, 0), NTYPES - 1);
        float rdeg = 1.f / deg[i];
        float4 hv = ((const float4*)hs[wv])[c];
        float4 Sv = ((const float4*)S)[ti * 32 + c];
        float4 m;
        m.x = (Sv.x - hv.x + tt.x) * rdeg;
        m.y = (Sv.y - hv.y + tt.y) * rdeg;
        m.z = (Sv.z - hv.z + tt.z) * rdeg;
        m.w = (Sv.w - hv.w + tt.w) * rdeg;
        ((float4*)ms[wv])[c] = m;
    }
    __syncthreads();   // the ONLY block-wide barrier

    // ---- matmul: wave `row` computes hout[row][:]. lane = (kh, c4):
    //      c4 = output float4 chunk (0..31), kh = k-half (0/1). ----
    int c4 = lane & 31;
    int kh = lane >> 5;
    int row = wv;
    const float4* __restrict__ WTl4 = (const float4*)WTl;
    const float4* __restrict__ WTr4 = (const float4*)WTr;
    const float* msr = ms[row];
    const float* hsr = hs[row];
    int kbase = kh * 64;
    float4 acc = {0.f, 0.f, 0.f, 0.f};
    #pragma unroll 4
    for (int kk = 0; kk < 64; ++kk) {
        int k = kbase + kk;
        float4 wl = WTl4[k * 32 + c4];   // lanes 0..31: 512B contiguous
        float4 wr = WTr4[k * 32 + c4];
        float mk = msr[k];               // LDS broadcast
        float hk = hsr[k];
        acc.x += mk * wl.x + hk * wr.x;
        acc.y += mk * wl.y + hk * wr.y;
        acc.z += mk * wl.z + hk * wr.z;
        acc.w += mk * wl.w + hk * wr.w;
    }
    acc.x += __shfl_down(acc.x, 32);
    acc.y += __shfl_down(acc.y, 32);
    acc.z += __shfl_down(acc.z, 32);
    acc.w += __shfl_down(acc.w, 32);
    if (kh == 0) {
        float4 bv = ((const float4*)bl)[c4];
        float4 o4;
        o4.x = fmaxf(acc.x + bv.x, 0.f);
        o4.y = fmaxf(acc.y + bv.y, 0.f);
        o4.z = fmaxf(acc.z + bv.z, 0.f);
        o4.w = fmaxf(acc.w + bv.w, 0.f);
        ((float4*)(hout + (size_t)i * HH))[c4] = o4;
    }
}

// ---------------------------------------------------------------------------
// Kernel E: batchnorm stats (sum, sumsq per column)
// ---------------------------------------------------------------------------
__global__ __launch_bounds__(HH) void bn_stats(
    const float* __restrict__ h, float* __restrict__ musum,
    float* __restrict__ varsum)
{
    int k = threadIdx.x;
    int base = blockIdx.x * 128;
    float s = 0.f, s2 = 0.f;
    for (int r = 0; r < 128; ++r) {
        float v = h[(size_t)(base + r) * HH + k];
        s += v; s2 += v * v;
    }
    atomicAdd(&musum[k], s);
    atomicAdd(&varsum[k], s2);
}

// ---------------------------------------------------------------------------
// Kernel F: BN apply + head, one wave per row, zero barriers.
// ---------------------------------------------------------------------------
__global__ __launch_bounds__(256) void finalize(
    const float* __restrict__ h, const float* __restrict__ musum,
    const float* __restrict__ varsum, const float* __restrict__ gamma,
    const float* __restrict__ beta, const float* __restrict__ Wo,
    const float* __restrict__ bo, float* __restrict__ out_h,
    float* __restrict__ out_o)
{
    int t = threadIdx.x;
    int wv = t >> 6;
    int lane = t & 63;
    int i = blockIdx.x * 4 + wv;

    float2 mus = ((const float2*)musum)[lane];
    float2 vas = ((const float2*)varsum)[lane];
    float2 ga  = ((const float2*)gamma)[lane];
    float2 be  = ((const float2*)beta)[lane];
    float mu0 = mus.x * (1.f / NN), mu1 = mus.y * (1.f / NN);
    float v0 = vas.x * (1.f / NN) - mu0 * mu0;
    float v1 = vas.y * (1.f / NN) - mu1 * mu1;
    float sc0 = ga.x / sqrtf(v0 + BN_EPS), sc1 = ga.y / sqrtf(v1 + BN_EPS);
    float sh0 = be.x - mu0 * sc0, sh1 = be.y - mu1 * sc1;

    float2 hv = ((const float2*)(h + (size_t)i * HH))[lane];
    float2 hb;
    hb.x = hv.x * sc0 + sh0;
    hb.y = hv.y * sc1 + sh1;
    ((float2*)(out_h + (size_t)i * HH))[lane] = hb;

    float2 w0 = ((const float2*)Wo)[lane];
    float2 w1 = ((const float2*)(Wo + HH))[lane];
    float2 w2 = ((const float2*)(Wo + 2 * HH))[lane];
    float p0 = hb.x * w0.x + hb.y * w0.y;
    float p1 = hb.x * w1.x + hb.y * w1.y;
    float p2 = hb.x * w2.x + hb.y * w2.y;
    for (int s = 32; s; s >>= 1) {
        p0 += __shfl_down(p0, s);
        p1 += __shfl_down(p1, s);
        p2 += __shfl_down(p2, s);
    }
    if (lane == 0) {
        out_o[(size_t)i * OUTD + 0] = p0 + bo[0];
        out_o[(size_t)i * OUTD + 1] = p1 + bo[1];
        out_o[(size_t)i * OUTD + 2] = p2 + bo[2];
    }
}

// ---------------------------------------------------------------------------
extern "C" void kernel_launch(void* const* d_in, const int* in_sizes, int n_in,
                              void* d_out, int out_size, void* d_ws, size_t ws_size,
                              hipStream_t stream)
{
    (void)in_sizes; (void)n_in; (void)out_size; (void)ws_size;
    const float* x_now = (const float*)d_in[0];
    const int*   sat   = (const int*)d_in[1];
    const float* Wl    = (const float*)d_in[2];
    const float* bl    = (const float*)d_in[3];
    const float* Wr    = (const float*)d_in[4];
    const float* gamma = (const float*)d_in[5];
    const float* beta  = (const float*)d_in[6];
    const float* Wo    = (const float*)d_in[7];
    const float* bo    = (const float*)d_in[8];

    float* ws = (float*)d_ws;
    float* x0 = ws;                          // 524288 floats
    float* h1 = x0 + (size_t)NN * HH;        // 524288
    float* h2 = h1 + (size_t)NN * HH;        // 524288
    float* WT = h2 + (size_t)NN * HH;        // 4*16384 = 65536 (Wl0,Wl1,Wr0,Wr1)
    float4* fn = (float4*)(WT + 65536);                // 4096 float4
    unsigned* mask = (unsigned*)((float*)fn + 4 * NN); // 524288 words
    float* deg = (float*)(mask + (size_t)NN * 128);    // 4096
    int* cnt = (int*)(deg + NN);             // 8 ints
    float* S0 = (float*)(cnt + 8);           // 768
    float* S1 = S0 + NTYPES * HH;            // 768
    float* musum = S1 + NTYPES * HH;         // 128
    float* varsum = musum + HH;              // 128

    size_t zero_bytes = (8 + 2 * NTYPES * HH + 2 * HH) * sizeof(float);
    hipMemsetAsync(cnt, 0, zero_bytes, stream);

    transpose_w<<<4, 256, 0, stream>>>(Wl, Wr, WT);
    type_hist<<<4, 256, 0, stream>>>(sat, cnt);
    build_x_fn<<<NN, HH, 0, stream>>>(x_now, x0, fn);
    build_mask<<<NN / MROW, HH, 0, stream>>>(fn, sat, cnt, mask, deg);

    type_sums<<<32, HH, 0, stream>>>(x0, sat, S0);
    layer_kernel<<<NN / LRPB, 256, 0, stream>>>(x0, mask, deg, S0, sat,
                                                WT, bl, WT + 32768, h1);
    type_sums<<<32, HH, 0, stream>>>(h1, sat, S1);
    layer_kernel<<<NN / LRPB, 256, 0, stream>>>(h1, mask, deg, S1, sat,
                                                WT + 16384, bl + HH, WT + 49152, h2);

    bn_stats<<<32, HH, 0, stream>>>(h2, musum, varsum);
    finalize<<<NN / 4, 256, 0, stream>>>(h2, musum, varsum, gamma, beta, Wo, bo,
                                         (float*)d_out, (float*)d_out + (size_t)NN * HH);
}

// Round 6
// 183.196 us; speedup vs baseline: 1.1243x; 1.0118x over previous
//
#include <hip/hip_runtime.h>
#include <hip/hip_bf16.h>
#include <math.h>

#define NN 4096
#define DD 127
#define HH 128
#define OUTD 3
#define NTYPES 6
#define SIM_THRESH 0.9f
#define BN_EPS 1e-5f
#define MROW 4    // rows per block in build_mask: amortizes fn reads 4x
#define LRPB 4    // rows per block in layer_kernel (one wave per row)
// Per-row neighbor list capacity. Degree is Binomial(~3413, 0.05):
// mean 171, sigma 13 -> 512 is a ~27-sigma bound. LDS 4KB/block.
#define LMAX 512

// ---------------------------------------------------------------------------
// Kernel T v2: transpose the 4 weight matrices into WT[k][o], 32 blocks
// (8 per matrix, 16 src rows each) so it isn't 4-CU latency-bound.
// ---------------------------------------------------------------------------
__global__ __launch_bounds__(256) void transpose_w(
    const float* __restrict__ Wl, const float* __restrict__ Wr,
    float* __restrict__ WT)
{
    int m = blockIdx.x >> 3;       // 0:Wl0 1:Wl1 2:Wr0 3:Wr1
    int p = blockIdx.x & 7;        // row-tile 0..7 (16 rows each)
    const float* src = ((m < 2) ? (Wl + m * 16384) : (Wr + (m - 2) * 16384))
                       + p * 16 * 128;
    float* dst = WT + m * 16384 + p * 16;
    __shared__ float lds[16][129];
    int t = threadIdx.x;
    #pragma unroll
    for (int it = 0; it < 8; ++it) {
        int lin = it * 256 + t;            // 2048 elements
        int o = lin >> 7, k = lin & 127;
        lds[o][k] = src[lin];              // coalesced read
    }
    __syncthreads();
    #pragma unroll
    for (int it = 0; it < 8; ++it) {
        int lin = it * 256 + t;
        int k = lin >> 4, oo = lin & 15;
        dst[k * 128 + oo] = lds[oo][k];    // 64B runs; pad 129 kills conflicts
    }
}

// ---------------------------------------------------------------------------
// Kernel H: per-type histogram, shuffle-reduced (96 global atomics total).
// ---------------------------------------------------------------------------
__global__ __launch_bounds__(256) void type_hist(
    const int* __restrict__ sat, int* __restrict__ cnt)
{
    int gid = blockIdx.x * 256 + threadIdx.x;
    int lane = threadIdx.x & 63;
    int cc[NTYPES] = {0, 0, 0, 0, 0, 0};
    for (int i = gid; i < NN; i += 4 * 256) {
        int s = sat[i]; s = min(max(s, 0), NTYPES - 1);
        #pragma unroll
        for (int t = 0; t < NTYPES; ++t) cc[t] += (s == t);
    }
    #pragma unroll
    for (int t = 0; t < NTYPES; ++t) {
        int v = cc[t];
        for (int s = 32; s; s >>= 1) v += __shfl_down(v, s);
        if (lane == 0 && v) atomicAdd(&cnt[t], v);
    }
}

// ---------------------------------------------------------------------------
// Kernel A: x = concat(x_now[:, :1], x_now) and fn[i]=normalize([x0,x0,x1,x2])
// ---------------------------------------------------------------------------
__global__ __launch_bounds__(HH) void build_x_fn(
    const float* __restrict__ x_now,
    float* __restrict__ x, float4* __restrict__ fn)
{
    int i = blockIdx.x;
    int k = threadIdx.x;
    const float* row = x_now + (size_t)i * DD;
    float v = (k == 0) ? row[0] : row[k - 1];
    x[(size_t)i * HH + k] = v;
    if (k == 0) {
        float f0 = row[0], f2 = row[1], f3 = row[2];
        float nrm = sqrtf(2.f * f0 * f0 + f2 * f2 + f3 * f3);
        nrm = fmaxf(nrm, 1e-12f);
        float inv = 1.f / nrm;
        fn[i] = make_float4(f0 * inv, f0 * inv, f2 * inv, f3 * inv);
    }
}

// ---------------------------------------------------------------------------
// Kernel B: cross-type cosine adjacency bitmask + degree, MROW rows/block.
// Bit layout: word w (0..127) of row i, bit b (0..31) <-> j = b*128 + w.
// ---------------------------------------------------------------------------
__global__ __launch_bounds__(HH) void build_mask(
    const float4* __restrict__ fn, const int* __restrict__ sat,
    const int* __restrict__ cnt, unsigned* __restrict__ mask,
    float* __restrict__ deg)
{
    int i0 = blockIdx.x * MROW;
    int w = threadIdx.x;  // 0..127
    float4 fi[MROW];
    int ti[MROW];
    #pragma unroll
    for (int r = 0; r < MROW; ++r) {
        fi[r] = fn[i0 + r];
        int t = sat[i0 + r];
        ti[r] = min(max(t, 0), NTYPES - 1);
    }
    unsigned word[MROW] = {0, 0, 0, 0};
    for (int b = 0; b < 32; ++b) {
        int j = b * 128 + w;
        float4 fj = fn[j];
        int tj = sat[j];
        #pragma unroll
        for (int r = 0; r < MROW; ++r) {
            float dot = fi[r].x * fj.x + fi[r].y * fj.y
                      + fi[r].z * fj.z + fi[r].w * fj.w;
            if (tj != ti[r] && dot > SIM_THRESH) word[r] |= (1u << b);
        }
    }
    int pcs[MROW];
    #pragma unroll
    for (int r = 0; r < MROW; ++r) {
        mask[(size_t)(i0 + r) * 128 + w] = word[r];
        pcs[r] = __popc(word[r]);
    }
    int lane = w & 63, wv = w >> 6;
    for (int s = 32; s; s >>= 1) {
        #pragma unroll
        for (int r = 0; r < MROW; ++r) pcs[r] += __shfl_down(pcs[r], s);
    }
    __shared__ int wt[2][MROW];
    if (lane == 0) {
        #pragma unroll
        for (int r = 0; r < MROW; ++r) wt[wv][r] = pcs[r];
    }
    __syncthreads();
    if (w < MROW) {
        int r = w;
        int tt = sat[i0 + r]; tt = min(max(tt, 0), NTYPES - 1);
        float d = (float)(cnt[tt] - 1 + wt[0][r] + wt[1][r]);
        deg[i0 + r] = fmaxf(d, 1.0f);
    }
}

// ---------------------------------------------------------------------------
// Kernel C: per-type column sums S[t][k] = sum_{i: type(i)=t} h[i][k]
// 64 blocks x 64 rows each.
// ---------------------------------------------------------------------------
__global__ __launch_bounds__(HH) void type_sums(
    const float* __restrict__ h, const int* __restrict__ sat,
    float* __restrict__ S)
{
    int k = threadIdx.x;
    int base = blockIdx.x * 64;
    __shared__ float ls[NTYPES][HH];
    for (int t = 0; t < NTYPES; ++t) ls[t][k] = 0.f;
    for (int r = 0; r < 64; ++r) {
        int i = base + r;
        int t = sat[i]; t = min(max(t, 0), NTYPES - 1);
        ls[t][k] += h[(size_t)i * HH + k];
    }
    for (int t = 0; t < NTYPES; ++t) atomicAdd(&S[t * HH + k], ls[t][k]);
}

// ---------------------------------------------------------------------------
// Kernel D v5: one WAVE per row. LMAX=512 (27-sigma degree bound) shrinks
// LDS to ~8.4KB/block; __launch_bounds__(256,8) -> 8 blocks/CU = 32
// waves/CU, doubling latency-hiding TLP over v4 (R4/R5 were 16 waves/CU,
// VALUBusy 17% -> latency-bound on list->gather dependent chains).
// ---------------------------------------------------------------------------
__global__ __launch_bounds__(256, 8) void layer_kernel(
    const float* __restrict__ h, const unsigned* __restrict__ mask,
    const float* __restrict__ deg, const float* __restrict__ S,
    const int* __restrict__ sat,
    const float* __restrict__ WTl, const float* __restrict__ bl,
    const float* __restrict__ WTr, float* __restrict__ hout)
{
    int t = threadIdx.x;
    int wv = t >> 6;          // wave id = row slot 0..3
    int lane = t & 63;
    int i0 = blockIdx.x * LRPB;
    int i = i0 + wv;

    __shared__ unsigned short list[LRPB][LMAX];          // 4 KB
    __shared__ __align__(16) float hs[LRPB][HH];         // 2 KB
    __shared__ __align__(16) float ms[LRPB][HH];         // 2 KB

    // ---- decode: each lane owns mask words lane and lane+64 ----
    const unsigned* mrow = mask + (size_t)i * 128;
    unsigned w0 = mrow[lane];
    unsigned w1 = mrow[lane + 64];
    int pc = __popc(w0) + __popc(w1);
    int x = pc;
    for (int s = 1; s < 64; s <<= 1) {
        int v = __shfl_up(x, s);
        if (lane >= s) x += v;
    }
    int ncnt = __shfl(x, 63);
    int ofs = x - pc;
    unsigned ww = w0;
    while (ww) {
        int b = __ffs(ww) - 1; ww &= ww - 1;
        list[wv][ofs++] = (unsigned short)(b * 128 + lane);
    }
    ww = w1;
    while (ww) {
        int b = __ffs(ww) - 1; ww &= ww - 1;
        list[wv][ofs++] = (unsigned short)(b * 128 + lane + 64);
    }
    ((float2*)hs[wv])[lane] = ((const float2*)(h + (size_t)i * HH))[lane];

    // ---- gather: q = neighbor slot (0/1), c = float4 chunk (0..31) ----
    int q = lane >> 5;
    int c = lane & 31;
    const float4* __restrict__ h4 = (const float4*)h;
    float4 a0 = {0,0,0,0}, a1 = {0,0,0,0}, a2 = {0,0,0,0}, a3 = {0,0,0,0};
    int g = 0;
    for (; g + 8 <= ncnt; g += 8) {
        int j0 = list[wv][g + q];
        int j1 = list[wv][g + 2 + q];
        int j2 = list[wv][g + 4 + q];
        int j3 = list[wv][g + 6 + q];
        float4 v0 = h4[j0 * 32 + c];
        float4 v1 = h4[j1 * 32 + c];
        float4 v2 = h4[j2 * 32 + c];
        float4 v3 = h4[j3 * 32 + c];
        a0.x += v0.x; a0.y += v0.y; a0.z += v0.z; a0.w += v0.w;
        a1.x += v1.x; a1.y += v1.y; a1.z += v1.z; a1.w += v1.w;
        a2.x += v2.x; a2.y += v2.y; a2.z += v2.z; a2.w += v2.w;
        a3.x += v3.x; a3.y += v3.y; a3.z += v3.z; a3.w += v3.w;
    }
    for (; g + 2 <= ncnt; g += 2) {
        int j0 = list[wv][g + q];
        float4 v0 = h4[j0 * 32 + c];
        a0.x += v0.x; a0.y += v0.y; a0.z += v0.z; a0.w += v0.w;
    }
    if (q < ncnt - g) {
        int j0 = list[wv][g + q];
        float4 v0 = h4[j0 * 32 + c];
        a1.x += v0.x; a1.y += v0.y; a1.z += v0.z; a1.w += v0.w;
    }
    float4 tt;
    tt.x = a0.x + a1.x + a2.x + a3.x;
    tt.y = a0.y + a1.y + a2.y + a3.y;
    tt.z = a0.z + a1.z + a2.z + a3.z;
    tt.w = a0.w + a1.w + a2.w + a3.w;
    tt.x += __shfl_down(tt.x, 32);
    tt.y += __shfl_down(tt.y, 32);
    tt.z += __shfl_down(tt.z, 32);
    tt.w += __shfl_down(tt.w, 32);
    if (q == 0) {
        int ti = sat[i]; ti = min(max(ti, 0), NTYPES - 1);
        float rdeg = 1.f / deg[i];
        float4 hv = ((const float4*)hs[wv])[c];
        float4 Sv = ((const float4*)S)[ti * 32 + c];
        float4 m;
        m.x = (Sv.x - hv.x + tt.x) * rdeg;
        m.y = (Sv.y - hv.y + tt.y) * rdeg;
        m.z = (Sv.z - hv.z + tt.z) * rdeg;
        m.w = (Sv.w - hv.w + tt.w) * rdeg;
        ((float4*)ms[wv])[c] = m;
    }
    __syncthreads();   // the ONLY block-wide barrier

    // ---- matmul: wave `row` computes hout[row][:]. lane = (kh, c4) ----
    int c4 = lane & 31;
    int kh = lane >> 5;
    int row = wv;
    const float4* __restrict__ WTl4 = (const float4*)WTl;
    const float4* __restrict__ WTr4 = (const float4*)WTr;
    const float* msr = ms[row];
    const float* hsr = hs[row];
    int kbase = kh * 64;
    float4 acc = {0.f, 0.f, 0.f, 0.f};
    #pragma unroll 4
    for (int kk = 0; kk < 64; ++kk) {
        int k = kbase + kk;
        float4 wl = WTl4[k * 32 + c4];   // lanes 0..31: 512B contiguous
        float4 wr = WTr4[k * 32 + c4];
        float mk = msr[k];               // LDS broadcast
        float hk = hsr[k];
        acc.x += mk * wl.x + hk * wr.x;
        acc.y += mk * wl.y + hk * wr.y;
        acc.z += mk * wl.z + hk * wr.z;
        acc.w += mk * wl.w + hk * wr.w;
    }
    acc.x += __shfl_down(acc.x, 32);
    acc.y += __shfl_down(acc.y, 32);
    acc.z += __shfl_down(acc.z, 32);
    acc.w += __shfl_down(acc.w, 32);
    if (kh == 0) {
        float4 bv = ((const float4*)bl)[c4];
        float4 o4;
        o4.x = fmaxf(acc.x + bv.x, 0.f);
        o4.y = fmaxf(acc.y + bv.y, 0.f);
        o4.z = fmaxf(acc.z + bv.z, 0.f);
        o4.w = fmaxf(acc.w + bv.w, 0.f);
        ((float4*)(hout + (size_t)i * HH))[c4] = o4;
    }
}

// ---------------------------------------------------------------------------
// Kernel E: batchnorm stats (sum, sumsq per column)
// ---------------------------------------------------------------------------
__global__ __launch_bounds__(HH) void bn_stats(
    const float* __restrict__ h, float* __restrict__ musum,
    float* __restrict__ varsum)
{
    int k = threadIdx.x;
    int base = blockIdx.x * 64;
    float s = 0.f, s2 = 0.f;
    for (int r = 0; r < 64; ++r) {
        float v = h[(size_t)(base + r) * HH + k];
        s += v; s2 += v * v;
    }
    atomicAdd(&musum[k], s);
    atomicAdd(&varsum[k], s2);
}

// ---------------------------------------------------------------------------
// Kernel F: BN apply + head, one wave per row, zero barriers.
// ---------------------------------------------------------------------------
__global__ __launch_bounds__(256) void finalize(
    const float* __restrict__ h, const float* __restrict__ musum,
    const float* __restrict__ varsum, const float* __restrict__ gamma,
    const float* __restrict__ beta, const float* __restrict__ Wo,
    const float* __restrict__ bo, float* __restrict__ out_h,
    float* __restrict__ out_o)
{
    int t = threadIdx.x;
    int wv = t >> 6;
    int lane = t & 63;
    int i = blockIdx.x * 4 + wv;

    float2 mus = ((const float2*)musum)[lane];
    float2 vas = ((const float2*)varsum)[lane];
    float2 ga  = ((const float2*)gamma)[lane];
    float2 be  = ((const float2*)beta)[lane];
    float mu0 = mus.x * (1.f / NN), mu1 = mus.y * (1.f / NN);
    float v0 = vas.x * (1.f / NN) - mu0 * mu0;
    float v1 = vas.y * (1.f / NN) - mu1 * mu1;
    float sc0 = ga.x / sqrtf(v0 + BN_EPS), sc1 = ga.y / sqrtf(v1 + BN_EPS);
    float sh0 = be.x - mu0 * sc0, sh1 = be.y - mu1 * sc1;

    float2 hv = ((const float2*)(h + (size_t)i * HH))[lane];
    float2 hb;
    hb.x = hv.x * sc0 + sh0;
    hb.y = hv.y * sc1 + sh1;
    ((float2*)(out_h + (size_t)i * HH))[lane] = hb;

    float2 w0 = ((const float2*)Wo)[lane];
    float2 w1 = ((const float2*)(Wo + HH))[lane];
    float2 w2 = ((const float2*)(Wo + 2 * HH))[lane];
    float p0 = hb.x * w0.x + hb.y * w0.y;
    float p1 = hb.x * w1.x + hb.y * w1.y;
    float p2 = hb.x * w2.x + hb.y * w2.y;
    for (int s = 32; s; s >>= 1) {
        p0 += __shfl_down(p0, s);
        p1 += __shfl_down(p1, s);
        p2 += __shfl_down(p2, s);
    }
    if (lane == 0) {
        out_o[(size_t)i * OUTD + 0] = p0 + bo[0];
        out_o[(size_t)i * OUTD + 1] = p1 + bo[1];
        out_o[(size_t)i * OUTD + 2] = p2 + bo[2];
    }
}

// ---------------------------------------------------------------------------
extern "C" void kernel_launch(void* const* d_in, const int* in_sizes, int n_in,
                              void* d_out, int out_size, void* d_ws, size_t ws_size,
                              hipStream_t stream)
{
    (void)in_sizes; (void)n_in; (void)out_size; (void)ws_size;
    const float* x_now = (const float*)d_in[0];
    const int*   sat   = (const int*)d_in[1];
    const float* Wl    = (const float*)d_in[2];
    const float* bl    = (const float*)d_in[3];
    const float* Wr    = (const float*)d_in[4];
    const float* gamma = (const float*)d_in[5];
    const float* beta  = (const float*)d_in[6];
    const float* Wo    = (const float*)d_in[7];
    const float* bo    = (const float*)d_in[8];

    float* ws = (float*)d_ws;
    float* x0 = ws;                          // 524288 floats
    float* h1 = x0 + (size_t)NN * HH;        // 524288
    float* h2 = h1 + (size_t)NN * HH;        // 524288
    float* WT = h2 + (size_t)NN * HH;        // 4*16384 = 65536 (Wl0,Wl1,Wr0,Wr1)
    float4* fn = (float4*)(WT + 65536);                // 4096 float4
    unsigned* mask = (unsigned*)((float*)fn + 4 * NN); // 524288 words
    float* deg = (float*)(mask + (size_t)NN * 128);    // 4096
    int* cnt = (int*)(deg + NN);             // 8 ints
    float* S0 = (float*)(cnt + 8);           // 768
    float* S1 = S0 + NTYPES * HH;            // 768
    float* musum = S1 + NTYPES * HH;         // 128
    float* varsum = musum + HH;              // 128

    size_t zero_bytes = (8 + 2 * NTYPES * HH + 2 * HH) * sizeof(float);
    hipMemsetAsync(cnt, 0, zero_bytes, stream);

    transpose_w<<<32, 256, 0, stream>>>(Wl, Wr, WT);
    type_hist<<<4, 256, 0, stream>>>(sat, cnt);
    build_x_fn<<<NN, HH, 0, stream>>>(x_now, x0, fn);
    build_mask<<<NN / MROW, HH, 0, stream>>>(fn, sat, cnt, mask, deg);

    type_sums<<<64, HH, 0, stream>>>(x0, sat, S0);
    layer_kernel<<<NN / LRPB, 256, 0, stream>>>(x0, mask, deg, S0, sat,
                                                WT, bl, WT + 32768, h1);
    type_sums<<<64, HH, 0, stream>>>(h1, sat, S1);
    layer_kernel<<<NN / LRPB, 256, 0, stream>>>(h1, mask, deg, S1, sat,
                                                WT + 16384, bl + HH, WT + 49152, h2);

    bn_stats<<<64, HH, 0, stream>>>(h2, musum, varsum);
    finalize<<<NN / 4, 256, 0, stream>>>(h2, musum, varsum, gamma, beta, Wo, bo,
                                         (float*)d_out, (float*)d_out + (size_t)NN * HH);
}

// Round 7
// 176.700 us; speedup vs baseline: 1.1656x; 1.0368x over previous
//
#include <hip/hip_runtime.h>
#include <hip/hip_bf16.h>
#include <math.h>

#define NN 4096
#define DD 127
#define HH 128
#define OUTD 3
#define NTYPES 6
#define SIM_THRESH 0.9f
#define BN_EPS 1e-5f
#define MROW 4    // rows per block in build_mask
#define LRPB 4    // rows per block in layer_kernel (one wave per row)
// Degree is Binomial(~3413, 0.05): mean 171, sigma 13 -> 512 = 27-sigma bound.
#define LMAX 512
#define NREP 8    // accumulator replicas (kills atomic same-address serialization)

// ---------------------------------------------------------------------------
// Kernel P (fused prep): blocks 0..31 transpose the 4 weight matrices into
// WT[k][o]; blocks 32..95 each own a 64-row strip: build x + fn, per-type
// histogram (ballot, 6 atomics/block), and S0 type-sums (768 atomics/block,
// one per (type,col)). Replaces 4 dispatches of R6 (transpose, hist,
// build_x_fn, type_sums) -> 1.
// ---------------------------------------------------------------------------
__global__ __launch_bounds__(256) void prep(
    const float* __restrict__ x_now, const int* __restrict__ sat,
    const float* __restrict__ Wl, const float* __restrict__ Wr,
    float* __restrict__ WT, float* __restrict__ x, float4* __restrict__ fn,
    int* __restrict__ cnt, float* __restrict__ S0)
{
    int t = threadIdx.x;
    if (blockIdx.x < 32) {
        // ---- weight transpose, 8 blocks per matrix ----
        int m = blockIdx.x >> 3;       // 0:Wl0 1:Wl1 2:Wr0 3:Wr1
        int p = blockIdx.x & 7;        // 16-row tile
        const float* src = ((m < 2) ? (Wl + m * 16384) : (Wr + (m - 2) * 16384))
                           + p * 16 * 128;
        float* dst = WT + m * 16384 + p * 16;
        __shared__ float lds[16][129];
        #pragma unroll
        for (int it = 0; it < 8; ++it) {
            int lin = it * 256 + t;
            int o = lin >> 7, k = lin & 127;
            lds[o][k] = src[lin];
        }
        __syncthreads();
        #pragma unroll
        for (int it = 0; it < 8; ++it) {
            int lin = it * 256 + t;
            int k = lin >> 4, oo = lin & 15;
            dst[k * 128 + oo] = lds[oo][k];
        }
        return;
    }

    // ---- 64-row strip: x, fn, hist, S0 ----
    int base = (blockIdx.x - 32) * 64;
    __shared__ int stypes[64];
    int myti = 0;
    if (t < 64) {
        int row = base + t;
        int ti = sat[row]; ti = min(max(ti, 0), NTYPES - 1);
        stypes[t] = ti; myti = ti;
        const float* rp = x_now + (size_t)row * DD;
        float f0 = rp[0], f2 = rp[1], f3 = rp[2];
        float nrm = fmaxf(sqrtf(2.f * f0 * f0 + f2 * f2 + f3 * f3), 1e-12f);
        float inv = 1.f / nrm;
        fn[row] = make_float4(f0 * inv, f0 * inv, f2 * inv, f3 * inv);
    }
    #pragma unroll
    for (int it = 0; it < 32; ++it) {
        int lin = it * 256 + t;
        int rl = lin >> 7, col = lin & 127;
        int row = base + rl;
        const float* rp = x_now + (size_t)row * DD;
        float v = (col == 0) ? rp[0] : rp[col - 1];
        x[(size_t)row * HH + col] = v;
    }
    __syncthreads();
    if (t < 64) {
        // wave-0 ballot histogram: 6 atomics per block
        #pragma unroll
        for (int tt = 0; tt < NTYPES; ++tt) {
            unsigned long long m = __ballot(myti == tt);
            if (t == 0) {
                int c = __popcll(m);
                if (c) atomicAdd(&cnt[tt], c);
            }
        }
    }
    if (t < 128) {
        // S0: per-column per-type partial over the strip, 1 atomic/(type,col)
        float acc[NTYPES] = {0.f, 0.f, 0.f, 0.f, 0.f, 0.f};
        for (int r = 0; r < 64; ++r) {
            float v = x[(size_t)(base + r) * HH + t];
            int tt = stypes[r];
            #pragma unroll
            for (int q = 0; q < NTYPES; ++q) acc[q] += (tt == q) ? v : 0.f;
        }
        #pragma unroll
        for (int q = 0; q < NTYPES; ++q) atomicAdd(&S0[q * HH + t], acc[q]);
    }
}

// ---------------------------------------------------------------------------
// Kernel B: cross-type cosine adjacency bitmask + degree, MROW rows/block.
// Bit layout: word w (0..127) of row i, bit b (0..31) <-> j = b*128 + w.
// ---------------------------------------------------------------------------
__global__ __launch_bounds__(HH) void build_mask(
    const float4* __restrict__ fn, const int* __restrict__ sat,
    const int* __restrict__ cnt, unsigned* __restrict__ mask,
    float* __restrict__ deg)
{
    int i0 = blockIdx.x * MROW;
    int w = threadIdx.x;  // 0..127
    float4 fi[MROW];
    int ti[MROW];
    #pragma unroll
    for (int r = 0; r < MROW; ++r) {
        fi[r] = fn[i0 + r];
        int t = sat[i0 + r];
        ti[r] = min(max(t, 0), NTYPES - 1);
    }
    unsigned word[MROW] = {0, 0, 0, 0};
    for (int b = 0; b < 32; ++b) {
        int j = b * 128 + w;
        float4 fj = fn[j];
        int tj = sat[j];
        #pragma unroll
        for (int r = 0; r < MROW; ++r) {
            float dot = fi[r].x * fj.x + fi[r].y * fj.y
                      + fi[r].z * fj.z + fi[r].w * fj.w;
            if (tj != ti[r] && dot > SIM_THRESH) word[r] |= (1u << b);
        }
    }
    int pcs[MROW];
    #pragma unroll
    for (int r = 0; r < MROW; ++r) {
        mask[(size_t)(i0 + r) * 128 + w] = word[r];
        pcs[r] = __popc(word[r]);
    }
    int lane = w & 63, wv = w >> 6;
    for (int s = 32; s; s >>= 1) {
        #pragma unroll
        for (int r = 0; r < MROW; ++r) pcs[r] += __shfl_down(pcs[r], s);
    }
    __shared__ int wt[2][MROW];
    if (lane == 0) {
        #pragma unroll
        for (int r = 0; r < MROW; ++r) wt[wv][r] = pcs[r];
    }
    __syncthreads();
    if (w < MROW) {
        int r = w;
        float d = (float)(cnt[ti[r]] - 1 + wt[0][r] + wt[1][r]);
        deg[i0 + r] = fmaxf(d, 1.0f);
    }
}

// ---------------------------------------------------------------------------
// Kernel D v6: one WAVE per row, fused epilogue.
// MODE 1: accumulate this block's 4 output rows into type-sums Sout
//         (NREP replicas, replica = blockIdx&7) for the next layer.
// MODE 2: accumulate sum / sumsq per column into musum8/varsum8 replicas
//         (fuses bn_stats).
// Input S has nrepS replicas (1 for S0 from prep, NREP for S1).
// ---------------------------------------------------------------------------
template <int MODE>
__global__ __launch_bounds__(256, 8) void layer_kernel(
    const float* __restrict__ h, const unsigned* __restrict__ mask,
    const float* __restrict__ deg, const float* __restrict__ S, int nrepS,
    const int* __restrict__ sat,
    const float* __restrict__ WTl, const float* __restrict__ bl,
    const float* __restrict__ WTr, float* __restrict__ hout,
    float* __restrict__ acc0, float* __restrict__ acc1)
{
    int t = threadIdx.x;
    int wv = t >> 6;          // wave id = row slot 0..3
    int lane = t & 63;
    int i0 = blockIdx.x * LRPB;
    int i = i0 + wv;

    __shared__ unsigned short list[LRPB][LMAX];          // 4 KB
    __shared__ __align__(16) float hs[LRPB][HH];         // 2 KB
    __shared__ __align__(16) float ms[LRPB][HH];         // 2 KB
    __shared__ int tarr[LRPB];

    if (t < LRPB) {
        int tt = sat[i0 + t];
        tarr[t] = min(max(tt, 0), NTYPES - 1);
    }

    // ---- decode: each lane owns mask words lane and lane+64 ----
    const unsigned* mrow = mask + (size_t)i * 128;
    unsigned w0 = mrow[lane];
    unsigned w1 = mrow[lane + 64];
    int pc = __popc(w0) + __popc(w1);
    int x = pc;
    for (int s = 1; s < 64; s <<= 1) {
        int v = __shfl_up(x, s);
        if (lane >= s) x += v;
    }
    int ncnt = __shfl(x, 63);
    int ofs = x - pc;
    unsigned ww = w0;
    while (ww) {
        int b = __ffs(ww) - 1; ww &= ww - 1;
        list[wv][ofs++] = (unsigned short)(b * 128 + lane);
    }
    ww = w1;
    while (ww) {
        int b = __ffs(ww) - 1; ww &= ww - 1;
        list[wv][ofs++] = (unsigned short)(b * 128 + lane + 64);
    }
    ((float2*)hs[wv])[lane] = ((const float2*)(h + (size_t)i * HH))[lane];

    // ---- gather: q = neighbor slot (0/1), c = float4 chunk (0..31) ----
    int q = lane >> 5;
    int c = lane & 31;
    const float4* __restrict__ h4 = (const float4*)h;
    float4 a0 = {0,0,0,0}, a1 = {0,0,0,0}, a2 = {0,0,0,0}, a3 = {0,0,0,0};
    int g = 0;
    for (; g + 8 <= ncnt; g += 8) {
        int j0 = list[wv][g + q];
        int j1 = list[wv][g + 2 + q];
        int j2 = list[wv][g + 4 + q];
        int j3 = list[wv][g + 6 + q];
        float4 v0 = h4[j0 * 32 + c];
        float4 v1 = h4[j1 * 32 + c];
        float4 v2 = h4[j2 * 32 + c];
        float4 v3 = h4[j3 * 32 + c];
        a0.x += v0.x; a0.y += v0.y; a0.z += v0.z; a0.w += v0.w;
        a1.x += v1.x; a1.y += v1.y; a1.z += v1.z; a1.w += v1.w;
        a2.x += v2.x; a2.y += v2.y; a2.z += v2.z; a2.w += v2.w;
        a3.x += v3.x; a3.y += v3.y; a3.z += v3.z; a3.w += v3.w;
    }
    for (; g + 2 <= ncnt; g += 2) {
        int j0 = list[wv][g + q];
        float4 v0 = h4[j0 * 32 + c];
        a0.x += v0.x; a0.y += v0.y; a0.z += v0.z; a0.w += v0.w;
    }
    if (q < ncnt - g) {
        int j0 = list[wv][g + q];
        float4 v0 = h4[j0 * 32 + c];
        a1.x += v0.x; a1.y += v0.y; a1.z += v0.z; a1.w += v0.w;
    }
    float4 tt;
    tt.x = a0.x + a1.x + a2.x + a3.x;
    tt.y = a0.y + a1.y + a2.y + a3.y;
    tt.z = a0.z + a1.z + a2.z + a3.z;
    tt.w = a0.w + a1.w + a2.w + a3.w;
    tt.x += __shfl_down(tt.x, 32);
    tt.y += __shfl_down(tt.y, 32);
    tt.z += __shfl_down(tt.z, 32);
    tt.w += __shfl_down(tt.w, 32);
    if (q == 0) {
        int ti = tarr[wv];
        float rdeg = 1.f / deg[i];
        float4 hv = ((const float4*)hs[wv])[c];
        float4 Sv = {0.f, 0.f, 0.f, 0.f};
        for (int rr = 0; rr < nrepS; ++rr) {
            float4 sv = ((const float4*)S)[(rr * NTYPES + ti) * 32 + c];
            Sv.x += sv.x; Sv.y += sv.y; Sv.z += sv.z; Sv.w += sv.w;
        }
        float4 m;
        m.x = (Sv.x - hv.x + tt.x) * rdeg;
        m.y = (Sv.y - hv.y + tt.y) * rdeg;
        m.z = (Sv.z - hv.z + tt.z) * rdeg;
        m.w = (Sv.w - hv.w + tt.w) * rdeg;
        ((float4*)ms[wv])[c] = m;
    }
    __syncthreads();

    // ---- matmul: wave `row` computes hout[row][:]. lane = (kh, c4) ----
    int c4 = lane & 31;
    int kh = lane >> 5;
    const float4* __restrict__ WTl4 = (const float4*)WTl;
    const float4* __restrict__ WTr4 = (const float4*)WTr;
    const float* msr = ms[wv];
    const float* hsr = hs[wv];
    int kbase = kh * 64;
    float4 acc = {0.f, 0.f, 0.f, 0.f};
    #pragma unroll 4
    for (int kk = 0; kk < 64; ++kk) {
        int k = kbase + kk;
        float4 wl = WTl4[k * 32 + c4];   // lanes 0..31: 512B contiguous
        float4 wr = WTr4[k * 32 + c4];
        float mk = msr[k];
        float hk = hsr[k];
        acc.x += mk * wl.x + hk * wr.x;
        acc.y += mk * wl.y + hk * wr.y;
        acc.z += mk * wl.z + hk * wr.z;
        acc.w += mk * wl.w + hk * wr.w;
    }
    acc.x += __shfl_down(acc.x, 32);
    acc.y += __shfl_down(acc.y, 32);
    acc.z += __shfl_down(acc.z, 32);
    acc.w += __shfl_down(acc.w, 32);
    if (kh == 0) {
        float4 bv = ((const float4*)bl)[c4];
        float4 o4;
        o4.x = fmaxf(acc.x + bv.x, 0.f);
        o4.y = fmaxf(acc.y + bv.y, 0.f);
        o4.z = fmaxf(acc.z + bv.z, 0.f);
        o4.w = fmaxf(acc.w + bv.w, 0.f);
        ((float4*)(hout + (size_t)i * HH))[c4] = o4;
        ((float4*)ms[wv])[c4] = o4;   // stage for fused epilogue (own-wave only)
    }
    __syncthreads();

    // ---- fused epilogue ----
    int rep = blockIdx.x & (NREP - 1);
    if (MODE == 1) {
        // next layer's type-sums, NREP replicas
        if (t < HH) {
            #pragma unroll
            for (int r = 0; r < LRPB; ++r)
                atomicAdd(&acc0[(rep * NTYPES + tarr[r]) * HH + t], ms[r][t]);
        }
    } else {
        // batchnorm sum / sumsq, NREP replicas
        if (t < HH) {
            float s = 0.f, s2 = 0.f;
            #pragma unroll
            for (int r = 0; r < LRPB; ++r) {
                float v = ms[r][t];
                s += v; s2 += v * v;
            }
            atomicAdd(&acc0[rep * HH + t], s);
            atomicAdd(&acc1[rep * HH + t], s2);
        }
    }
}

// ---------------------------------------------------------------------------
// Kernel F: BN apply + head, one wave per row; sums the NREP stat replicas.
// ---------------------------------------------------------------------------
__global__ __launch_bounds__(256) void finalize(
    const float* __restrict__ h, const float* __restrict__ musum8,
    const float* __restrict__ varsum8, const float* __restrict__ gamma,
    const float* __restrict__ beta, const float* __restrict__ Wo,
    const float* __restrict__ bo, float* __restrict__ out_h,
    float* __restrict__ out_o)
{
    int t = threadIdx.x;
    int wv = t >> 6;
    int lane = t & 63;
    int i = blockIdx.x * 4 + wv;

    float2 mus = {0.f, 0.f}, vas = {0.f, 0.f};
    #pragma unroll
    for (int r = 0; r < NREP; ++r) {
        float2 a = ((const float2*)(musum8 + r * HH))[lane];
        float2 b = ((const float2*)(varsum8 + r * HH))[lane];
        mus.x += a.x; mus.y += a.y;
        vas.x += b.x; vas.y += b.y;
    }
    float2 ga  = ((const float2*)gamma)[lane];
    float2 be  = ((const float2*)beta)[lane];
    float mu0 = mus.x * (1.f / NN), mu1 = mus.y * (1.f / NN);
    float v0 = vas.x * (1.f / NN) - mu0 * mu0;
    float v1 = vas.y * (1.f / NN) - mu1 * mu1;
    float sc0 = ga.x / sqrtf(v0 + BN_EPS), sc1 = ga.y / sqrtf(v1 + BN_EPS);
    float sh0 = be.x - mu0 * sc0, sh1 = be.y - mu1 * sc1;

    float2 hv = ((const float2*)(h + (size_t)i * HH))[lane];
    float2 hb;
    hb.x = hv.x * sc0 + sh0;
    hb.y = hv.y * sc1 + sh1;
    ((float2*)(out_h + (size_t)i * HH))[lane] = hb;

    float2 w0 = ((const float2*)Wo)[lane];
    float2 w1 = ((const float2*)(Wo + HH))[lane];
    float2 w2 = ((const float2*)(Wo + 2 * HH))[lane];
    float p0 = hb.x * w0.x + hb.y * w0.y;
    float p1 = hb.x * w1.x + hb.y * w1.y;
    float p2 = hb.x * w2.x + hb.y * w2.y;
    for (int s = 32; s; s >>= 1) {
        p0 += __shfl_down(p0, s);
        p1 += __shfl_down(p1, s);
        p2 += __shfl_down(p2, s);
    }
    if (lane == 0) {
        out_o[(size_t)i * OUTD + 0] = p0 + bo[0];
        out_o[(size_t)i * OUTD + 1] = p1 + bo[1];
        out_o[(size_t)i * OUTD + 2] = p2 + bo[2];
    }
}

// ---------------------------------------------------------------------------
extern "C" void kernel_launch(void* const* d_in, const int* in_sizes, int n_in,
                              void* d_out, int out_size, void* d_ws, size_t ws_size,
                              hipStream_t stream)
{
    (void)in_sizes; (void)n_in; (void)out_size; (void)ws_size;
    const float* x_now = (const float*)d_in[0];
    const int*   sat   = (const int*)d_in[1];
    const float* Wl    = (const float*)d_in[2];
    const float* bl    = (const float*)d_in[3];
    const float* Wr    = (const float*)d_in[4];
    const float* gamma = (const float*)d_in[5];
    const float* beta  = (const float*)d_in[6];
    const float* Wo    = (const float*)d_in[7];
    const float* bo    = (const float*)d_in[8];

    float* ws = (float*)d_ws;
    float* x0 = ws;                          // 524288 floats
    float* h1 = x0 + (size_t)NN * HH;        // 524288
    float* h2 = h1 + (size_t)NN * HH;        // 524288
    float* WT = h2 + (size_t)NN * HH;        // 65536 (Wl0,Wl1,Wr0,Wr1 transposed)
    float4* fn = (float4*)(WT + 65536);                // 4096 float4
    unsigned* mask = (unsigned*)((float*)fn + 4 * NN); // 524288 words
    float* deg = (float*)(mask + (size_t)NN * 128);    // 4096
    // ---- zeroed accumulator region (one contiguous memset) ----
    int*   cnt   = (int*)(deg + NN);                   // 8
    float* S0    = (float*)(cnt + 8);                  // 768
    float* S1rep = S0 + NTYPES * HH;                   // NREP*768 = 6144
    float* mu8   = S1rep + NREP * NTYPES * HH;         // NREP*128 = 1024
    float* var8  = mu8 + NREP * HH;                    // 1024

    size_t zero_bytes = (8 + NTYPES * HH + NREP * NTYPES * HH + 2 * NREP * HH)
                        * sizeof(float);
    hipMemsetAsync(cnt, 0, zero_bytes, stream);

    prep<<<96, 256, 0, stream>>>(x_now, sat, Wl, Wr, WT, x0, fn, cnt, S0);
    build_mask<<<NN / MROW, HH, 0, stream>>>(fn, sat, cnt, mask, deg);

    layer_kernel<1><<<NN / LRPB, 256, 0, stream>>>(
        x0, mask, deg, S0, 1, sat, WT, bl, WT + 32768, h1, S1rep, nullptr);
    layer_kernel<2><<<NN / LRPB, 256, 0, stream>>>(
        h1, mask, deg, S1rep, NREP, sat, WT + 16384, bl + HH, WT + 49152, h2,
        mu8, var8);

    finalize<<<NN / 4, 256, 0, stream>>>(h2, mu8, var8, gamma, beta, Wo, bo,
                                         (float*)d_out, (float*)d_out + (size_t)NN * HH);
}

// Round 8
// 169.607 us; speedup vs baseline: 1.2144x; 1.0418x over previous
//
#include <hip/hip_runtime.h>
#include <hip/hip_bf16.h>
#include <math.h>

#define NN 4096
#define DD 127
#define HH 128
#define OUTD 3
#define NTYPES 6
#define SIM_THRESH 0.9f
#define BN_EPS 1e-5f
#define MROW 4    // rows per block in build_mask
#define NREP 8    // accumulator replicas (kills atomic same-address serialization)
// Half-row neighbor list capacity. Half-degree is Binomial(~1706, 0.05):
// mean 85, sigma 9 -> 256 = 19-sigma bound.
#define LMAXH 256

// ---------------------------------------------------------------------------
// Kernel P (fused prep): blocks 0..31 transpose the 4 weight matrices into
// WT[k][o]; blocks 32..95 each own a 64-row strip: build x + fn, per-type
// histogram (ballot), and S0 type-sums.
// ---------------------------------------------------------------------------
__global__ __launch_bounds__(256) void prep(
    const float* __restrict__ x_now, const int* __restrict__ sat,
    const float* __restrict__ Wl, const float* __restrict__ Wr,
    float* __restrict__ WT, float* __restrict__ x, float4* __restrict__ fn,
    int* __restrict__ cnt, float* __restrict__ S0)
{
    int t = threadIdx.x;
    if (blockIdx.x < 32) {
        int m = blockIdx.x >> 3;       // 0:Wl0 1:Wl1 2:Wr0 3:Wr1
        int p = blockIdx.x & 7;        // 16-row tile
        const float* src = ((m < 2) ? (Wl + m * 16384) : (Wr + (m - 2) * 16384))
                           + p * 16 * 128;
        float* dst = WT + m * 16384 + p * 16;
        __shared__ float lds[16][129];
        #pragma unroll
        for (int it = 0; it < 8; ++it) {
            int lin = it * 256 + t;
            int o = lin >> 7, k = lin & 127;
            lds[o][k] = src[lin];
        }
        __syncthreads();
        #pragma unroll
        for (int it = 0; it < 8; ++it) {
            int lin = it * 256 + t;
            int k = lin >> 4, oo = lin & 15;
            dst[k * 128 + oo] = lds[oo][k];
        }
        return;
    }

    int base = (blockIdx.x - 32) * 64;
    __shared__ int stypes[64];
    int myti = 0;
    if (t < 64) {
        int row = base + t;
        int ti = sat[row]; ti = min(max(ti, 0), NTYPES - 1);
        stypes[t] = ti; myti = ti;
        const float* rp = x_now + (size_t)row * DD;
        float f0 = rp[0], f2 = rp[1], f3 = rp[2];
        float nrm = fmaxf(sqrtf(2.f * f0 * f0 + f2 * f2 + f3 * f3), 1e-12f);
        float inv = 1.f / nrm;
        fn[row] = make_float4(f0 * inv, f0 * inv, f2 * inv, f3 * inv);
    }
    #pragma unroll
    for (int it = 0; it < 32; ++it) {
        int lin = it * 256 + t;
        int rl = lin >> 7, col = lin & 127;
        int row = base + rl;
        const float* rp = x_now + (size_t)row * DD;
        float v = (col == 0) ? rp[0] : rp[col - 1];
        x[(size_t)row * HH + col] = v;
    }
    __syncthreads();
    if (t < 64) {
        #pragma unroll
        for (int tt = 0; tt < NTYPES; ++tt) {
            unsigned long long m = __ballot(myti == tt);
            if (t == 0) {
                int c = __popcll(m);
                if (c) atomicAdd(&cnt[tt], c);
            }
        }
    }
    if (t < 128) {
        float acc[NTYPES] = {0.f, 0.f, 0.f, 0.f, 0.f, 0.f};
        for (int r = 0; r < 64; ++r) {
            float v = x[(size_t)(base + r) * HH + t];
            int tt = stypes[r];
            #pragma unroll
            for (int q = 0; q < NTYPES; ++q) acc[q] += (tt == q) ? v : 0.f;
        }
        #pragma unroll
        for (int q = 0; q < NTYPES; ++q) atomicAdd(&S0[q * HH + t], acc[q]);
    }
}

// ---------------------------------------------------------------------------
// Kernel B: cross-type cosine adjacency bitmask + degree, MROW rows/block.
// Bit layout: word w (0..127) of row i, bit b (0..31) <-> j = b*128 + w.
// ---------------------------------------------------------------------------
__global__ __launch_bounds__(HH) void build_mask(
    const float4* __restrict__ fn, const int* __restrict__ sat,
    const int* __restrict__ cnt, unsigned* __restrict__ mask,
    float* __restrict__ deg)
{
    int i0 = blockIdx.x * MROW;
    int w = threadIdx.x;  // 0..127
    float4 fi[MROW];
    int ti[MROW];
    #pragma unroll
    for (int r = 0; r < MROW; ++r) {
        fi[r] = fn[i0 + r];
        int t = sat[i0 + r];
        ti[r] = min(max(t, 0), NTYPES - 1);
    }
    unsigned word[MROW] = {0, 0, 0, 0};
    for (int b = 0; b < 32; ++b) {
        int j = b * 128 + w;
        float4 fj = fn[j];
        int tj = sat[j];
        #pragma unroll
        for (int r = 0; r < MROW; ++r) {
            float dot = fi[r].x * fj.x + fi[r].y * fj.y
                      + fi[r].z * fj.z + fi[r].w * fj.w;
            if (tj != ti[r] && dot > SIM_THRESH) word[r] |= (1u << b);
        }
    }
    int pcs[MROW];
    #pragma unroll
    for (int r = 0; r < MROW; ++r) {
        mask[(size_t)(i0 + r) * 128 + w] = word[r];
        pcs[r] = __popc(word[r]);
    }
    int lane = w & 63, wv = w >> 6;
    for (int s = 32; s; s >>= 1) {
        #pragma unroll
        for (int r = 0; r < MROW; ++r) pcs[r] += __shfl_down(pcs[r], s);
    }
    __shared__ int wt[2][MROW];
    if (lane == 0) {
        #pragma unroll
        for (int r = 0; r < MROW; ++r) wt[wv][r] = pcs[r];
    }
    __syncthreads();
    if (w < MROW) {
        int r = w;
        float d = (float)(cnt[ti[r]] - 1 + wt[0][r] + wt[1][r]);
        deg[i0 + r] = fmaxf(d, 1.0f);
    }
}

// ---------------------------------------------------------------------------
// Kernel D v7: TWO waves per row (2 rows / 256-thread block, grid 2048).
// Doubles TLP to 32 waves/CU (R7: 16 waves/CU, VALUBusy 22% -> latency-
// bound). Wave (r,hf): decodes mask words [hf*64, hf*64+64) into its own
// list, gathers its half (6 loads in flight), partial -> LDS. Barrier,
// hf==0 wave combines + computes m. Barrier, matmul output-split (wave hf
// computes outputs [hf*64, hf*64+64), full k in-wave via 4-way k-split).
// Fused epilogue as in v6 (MODE 1: next-layer type sums; 2: BN stats).
// ---------------------------------------------------------------------------
template <int MODE>
__global__ __launch_bounds__(256, 8) void layer_kernel(
    const float* __restrict__ h, const unsigned* __restrict__ mask,
    const float* __restrict__ deg, const float* __restrict__ S, int nrepS,
    const int* __restrict__ sat,
    const float* __restrict__ WTl, const float* __restrict__ bl,
    const float* __restrict__ WTr, float* __restrict__ hout,
    float* __restrict__ acc0, float* __restrict__ acc1)
{
    int t = threadIdx.x;
    int wv = t >> 6;          // wave id 0..3
    int lane = t & 63;
    int r  = wv >> 1;         // row slot 0..1
    int hf = wv & 1;          // half 0..1
    int i0 = blockIdx.x * 2;
    int i = i0 + r;

    __shared__ unsigned short list[4][LMAXH];            // 2 KB
    __shared__ __align__(16) float hs[2][HH];            // 1 KB
    __shared__ __align__(16) float ms[2][HH];            // 1 KB
    __shared__ __align__(16) float part[4][HH];          // 2 KB (reused for out)
    __shared__ int tarr[2];

    if (t < 2) {
        int tt = sat[i0 + t];
        tarr[t] = min(max(tt, 0), NTYPES - 1);
    }

    // ---- decode: wave (r,hf) owns mask words hf*64+lane of row i ----
    int widx = hf * 64 + lane;
    unsigned word = mask[(size_t)i * 128 + widx];
    int pc = __popc(word);
    int x = pc;
    for (int s = 1; s < 64; s <<= 1) {
        int v = __shfl_up(x, s);
        if (lane >= s) x += v;
    }
    int ncnt = __shfl(x, 63);
    int ofs = x - pc;
    unsigned ww = word;
    while (ww) {
        int b = __ffs(ww) - 1; ww &= ww - 1;
        list[wv][ofs++] = (unsigned short)(b * 128 + widx);
    }
    if (hf == 0)
        ((float2*)hs[r])[lane] = ((const float2*)(h + (size_t)i * HH))[lane];

    // ---- gather own half-list: 6 loads in flight, 12 neighbors/iter ----
    int q = lane >> 5;
    int c = lane & 31;
    const float4* __restrict__ h4 = (const float4*)h;
    float4 a0 = {0,0,0,0}, a1 = {0,0,0,0}, a2 = {0,0,0,0}, a3 = {0,0,0,0};
    int g = 0;
    for (; g + 12 <= ncnt; g += 12) {
        int j0 = list[wv][g + q];
        int j1 = list[wv][g + 2 + q];
        int j2 = list[wv][g + 4 + q];
        int j3 = list[wv][g + 6 + q];
        int j4 = list[wv][g + 8 + q];
        int j5 = list[wv][g + 10 + q];
        float4 v0 = h4[j0 * 32 + c];
        float4 v1 = h4[j1 * 32 + c];
        float4 v2 = h4[j2 * 32 + c];
        float4 v3 = h4[j3 * 32 + c];
        float4 v4 = h4[j4 * 32 + c];
        float4 v5 = h4[j5 * 32 + c];
        a0.x += v0.x; a0.y += v0.y; a0.z += v0.z; a0.w += v0.w;
        a1.x += v1.x; a1.y += v1.y; a1.z += v1.z; a1.w += v1.w;
        a2.x += v2.x; a2.y += v2.y; a2.z += v2.z; a2.w += v2.w;
        a3.x += v3.x; a3.y += v3.y; a3.z += v3.z; a3.w += v3.w;
        a0.x += v4.x; a0.y += v4.y; a0.z += v4.z; a0.w += v4.w;
        a1.x += v5.x; a1.y += v5.y; a1.z += v5.z; a1.w += v5.w;
    }
    for (; g + 2 <= ncnt; g += 2) {
        int j0 = list[wv][g + q];
        float4 v0 = h4[j0 * 32 + c];
        a0.x += v0.x; a0.y += v0.y; a0.z += v0.z; a0.w += v0.w;
    }
    if (q < ncnt - g) {
        int j0 = list[wv][g + q];
        float4 v0 = h4[j0 * 32 + c];
        a1.x += v0.x; a1.y += v0.y; a1.z += v0.z; a1.w += v0.w;
    }
    float4 tt;
    tt.x = a0.x + a1.x + a2.x + a3.x;
    tt.y = a0.y + a1.y + a2.y + a3.y;
    tt.z = a0.z + a1.z + a2.z + a3.z;
    tt.w = a0.w + a1.w + a2.w + a3.w;
    tt.x += __shfl_down(tt.x, 32);
    tt.y += __shfl_down(tt.y, 32);
    tt.z += __shfl_down(tt.z, 32);
    tt.w += __shfl_down(tt.w, 32);
    if (q == 0) ((float4*)part[wv])[c] = tt;
    __syncthreads();   // barrier 1: partials + tarr ready

    // ---- combine halves + m (hf==0 wave, lanes 0..31) ----
    if (hf == 0 && q == 0) {
        float4 p0 = ((const float4*)part[wv])[c];
        float4 p1 = ((const float4*)part[wv + 1])[c];
        int ti = tarr[r];
        float rdeg = 1.f / deg[i];
        float4 hv = ((const float4*)hs[r])[c];
        float4 Sv = {0.f, 0.f, 0.f, 0.f};
        for (int rr = 0; rr < nrepS; ++rr) {
            float4 sv = ((const float4*)S)[(rr * NTYPES + ti) * 32 + c];
            Sv.x += sv.x; Sv.y += sv.y; Sv.z += sv.z; Sv.w += sv.w;
        }
        float4 m;
        m.x = (Sv.x - hv.x + p0.x + p1.x) * rdeg;
        m.y = (Sv.y - hv.y + p0.y + p1.y) * rdeg;
        m.z = (Sv.z - hv.z + p0.z + p1.z) * rdeg;
        m.w = (Sv.w - hv.w + p0.w + p1.w) * rdeg;
        ((float4*)ms[r])[c] = m;
    }
    __syncthreads();   // barrier 2: ms ready; part free for reuse

    // ---- matmul: wave (r,hf) computes outputs c4 = hf*16+(lane&15);
    //      4-way k-split in wave: kh = lane>>4, k = kh*32+kk ----
    int c4 = hf * 16 + (lane & 15);
    int kh = lane >> 4;
    const float4* __restrict__ WTl4 = (const float4*)WTl;
    const float4* __restrict__ WTr4 = (const float4*)WTr;
    const float* msr = ms[r];
    const float* hsr = hs[r];
    int kbase = kh * 32;
    float4 acc = {0.f, 0.f, 0.f, 0.f};
    #pragma unroll 4
    for (int kk = 0; kk < 32; ++kk) {
        int k = kbase + kk;
        float4 wl = WTl4[k * 32 + c4];
        float4 wr = WTr4[k * 32 + c4];
        float mk = msr[k];
        float hk = hsr[k];
        acc.x += mk * wl.x + hk * wr.x;
        acc.y += mk * wl.y + hk * wr.y;
        acc.z += mk * wl.z + hk * wr.z;
        acc.w += mk * wl.w + hk * wr.w;
    }
    acc.x += __shfl_down(acc.x, 32);
    acc.y += __shfl_down(acc.y, 32);
    acc.z += __shfl_down(acc.z, 32);
    acc.w += __shfl_down(acc.w, 32);
    acc.x += __shfl_down(acc.x, 16);
    acc.y += __shfl_down(acc.y, 16);
    acc.z += __shfl_down(acc.z, 16);
    acc.w += __shfl_down(acc.w, 16);
    if (lane < 16) {
        float4 bv = ((const float4*)bl)[c4];
        float4 o4;
        o4.x = fmaxf(acc.x + bv.x, 0.f);
        o4.y = fmaxf(acc.y + bv.y, 0.f);
        o4.z = fmaxf(acc.z + bv.z, 0.f);
        o4.w = fmaxf(acc.w + bv.w, 0.f);
        ((float4*)(hout + (size_t)i * HH))[c4] = o4;
        ((float4*)part[r])[c4] = o4;    // stage for fused epilogue
    }
    __syncthreads();   // barrier 3: staged outputs ready

    // ---- fused epilogue ----
    int rep = blockIdx.x & (NREP - 1);
    if (MODE == 1) {
        if (t < HH) {
            #pragma unroll
            for (int rr = 0; rr < 2; ++rr)
                atomicAdd(&acc0[(rep * NTYPES + tarr[rr]) * HH + t], part[rr][t]);
        }
    } else {
        if (t < HH) {
            float s = 0.f, s2 = 0.f;
            #pragma unroll
            for (int rr = 0; rr < 2; ++rr) {
                float v = part[rr][t];
                s += v; s2 += v * v;
            }
            atomicAdd(&acc0[rep * HH + t], s);
            atomicAdd(&acc1[rep * HH + t], s2);
        }
    }
}

// ---------------------------------------------------------------------------
// Kernel F: BN apply + head, one wave per row; sums the NREP stat replicas.
// ---------------------------------------------------------------------------
__global__ __launch_bounds__(256) void finalize(
    const float* __restrict__ h, const float* __restrict__ musum8,
    const float* __restrict__ varsum8, const float* __restrict__ gamma,
    const float* __restrict__ beta, const float* __restrict__ Wo,
    const float* __restrict__ bo, float* __restrict__ out_h,
    float* __restrict__ out_o)
{
    int t = threadIdx.x;
    int wv = t >> 6;
    int lane = t & 63;
    int i = blockIdx.x * 4 + wv;

    float2 mus = {0.f, 0.f}, vas = {0.f, 0.f};
    #pragma unroll
    for (int r = 0; r < NREP; ++r) {
        float2 a = ((const float2*)(musum8 + r * HH))[lane];
        float2 b = ((const float2*)(varsum8 + r * HH))[lane];
        mus.x += a.x; mus.y += a.y;
        vas.x += b.x; vas.y += b.y;
    }
    float2 ga  = ((const float2*)gamma)[lane];
    float2 be  = ((const float2*)beta)[lane];
    float mu0 = mus.x * (1.f / NN), mu1 = mus.y * (1.f / NN);
    float v0 = vas.x * (1.f / NN) - mu0 * mu0;
    float v1 = vas.y * (1.f / NN) - mu1 * mu1;
    float sc0 = ga.x / sqrtf(v0 + BN_EPS), sc1 = ga.y / sqrtf(v1 + BN_EPS);
    float sh0 = be.x - mu0 * sc0, sh1 = be.y - mu1 * sc1;

    float2 hv = ((const float2*)(h + (size_t)i * HH))[lane];
    float2 hb;
    hb.x = hv.x * sc0 + sh0;
    hb.y = hv.y * sc1 + sh1;
    ((float2*)(out_h + (size_t)i * HH))[lane] = hb;

    float2 w0 = ((const float2*)Wo)[lane];
    float2 w1 = ((const float2*)(Wo + HH))[lane];
    float2 w2 = ((const float2*)(Wo + 2 * HH))[lane];
    float p0 = hb.x * w0.x + hb.y * w0.y;
    float p1 = hb.x * w1.x + hb.y * w1.y;
    float p2 = hb.x * w2.x + hb.y * w2.y;
    for (int s = 32; s; s >>= 1) {
        p0 += __shfl_down(p0, s);
        p1 += __shfl_down(p1, s);
        p2 += __shfl_down(p2, s);
    }
    if (lane == 0) {
        out_o[(size_t)i * OUTD + 0] = p0 + bo[0];
        out_o[(size_t)i * OUTD + 1] = p1 + bo[1];
        out_o[(size_t)i * OUTD + 2] = p2 + bo[2];
    }
}

// ---------------------------------------------------------------------------
extern "C" void kernel_launch(void* const* d_in, const int* in_sizes, int n_in,
                              void* d_out, int out_size, void* d_ws, size_t ws_size,
                              hipStream_t stream)
{
    (void)in_sizes; (void)n_in; (void)out_size; (void)ws_size;
    const float* x_now = (const float*)d_in[0];
    const int*   sat   = (const int*)d_in[1];
    const float* Wl    = (const float*)d_in[2];
    const float* bl    = (const float*)d_in[3];
    const float* Wr    = (const float*)d_in[4];
    const float* gamma = (const float*)d_in[5];
    const float* beta  = (const float*)d_in[6];
    const float* Wo    = (const float*)d_in[7];
    const float* bo    = (const float*)d_in[8];

    float* ws = (float*)d_ws;
    float* x0 = ws;                          // 524288 floats
    float* h1 = x0 + (size_t)NN * HH;        // 524288
    float* h2 = h1 + (size_t)NN * HH;        // 524288
    float* WT = h2 + (size_t)NN * HH;        // 65536 (Wl0,Wl1,Wr0,Wr1 transposed)
    float4* fn = (float4*)(WT + 65536);                // 4096 float4
    unsigned* mask = (unsigned*)((float*)fn + 4 * NN); // 524288 words
    float* deg = (float*)(mask + (size_t)NN * 128);    // 4096
    // ---- zeroed accumulator region (one contiguous memset) ----
    int*   cnt   = (int*)(deg + NN);                   // 8
    float* S0    = (float*)(cnt + 8);                  // 768
    float* S1rep = S0 + NTYPES * HH;                   // NREP*768 = 6144
    float* mu8   = S1rep + NREP * NTYPES * HH;         // NREP*128 = 1024
    float* var8  = mu8 + NREP * HH;                    // 1024

    size_t zero_bytes = (8 + NTYPES * HH + NREP * NTYPES * HH + 2 * NREP * HH)
                        * sizeof(float);
    hipMemsetAsync(cnt, 0, zero_bytes, stream);

    prep<<<96, 256, 0, stream>>>(x_now, sat, Wl, Wr, WT, x0, fn, cnt, S0);
    build_mask<<<NN / MROW, HH, 0, stream>>>(fn, sat, cnt, mask, deg);

    layer_kernel<1><<<NN / 2, 256, 0, stream>>>(
        x0, mask, deg, S0, 1, sat, WT, bl, WT + 32768, h1, S1rep, nullptr);
    layer_kernel<2><<<NN / 2, 256, 0, stream>>>(
        h1, mask, deg, S1rep, NREP, sat, WT + 16384, bl + HH, WT + 49152, h2,
        mu8, var8);

    finalize<<<NN / 4, 256, 0, stream>>>(h2, mu8, var8, gamma, beta, Wo, bo,
                                         (float*)d_out, (float*)d_out + (size_t)NN * HH);
}

// Round 9
// 160.040 us; speedup vs baseline: 1.2870x; 1.0598x over previous
//
#include <hip/hip_runtime.h>
#include <hip/hip_bf16.h>
#include <math.h>

#define NN 4096
#define DD 127
#define HH 128
#define OUTD 3
#define NTYPES 6
#define SIM_THRESH 0.9f
#define BN_EPS 1e-5f
#define MROW 4    // rows per block in build_mask
#define NREP 8    // accumulator replicas (kills atomic same-address serialization)
// Half-row neighbor list capacity. Half-degree is Binomial(~1706, 0.05):
// mean 85, sigma 9 -> 256 = 19-sigma bound.
#define LMAXH 256

typedef unsigned short ushortT;

// round-to-nearest-even fp32 -> bf16 (bit pattern)
static __device__ inline ushortT f2bf(float f) {
    unsigned u = __float_as_uint(f);
    unsigned r = (u + 0x7fffu + ((u >> 16) & 1u)) >> 16;
    return (ushortT)r;
}

// ---------------------------------------------------------------------------
// Kernel P (fused prep): blocks 0..31 transpose the 4 weight matrices into
// WT[k][o]; blocks 32..95 each own a 64-row strip: build x (fp32 + bf16
// gather replica), fn, per-type histogram (ballot), and S0 type-sums.
// ---------------------------------------------------------------------------
__global__ __launch_bounds__(256) void prep(
    const float* __restrict__ x_now, const int* __restrict__ sat,
    const float* __restrict__ Wl, const float* __restrict__ Wr,
    float* __restrict__ WT, float* __restrict__ x, ushortT* __restrict__ xbf,
    float4* __restrict__ fn, int* __restrict__ cnt, float* __restrict__ S0)
{
    int t = threadIdx.x;
    if (blockIdx.x < 32) {
        int m = blockIdx.x >> 3;       // 0:Wl0 1:Wl1 2:Wr0 3:Wr1
        int p = blockIdx.x & 7;        // 16-row tile
        const float* src = ((m < 2) ? (Wl + m * 16384) : (Wr + (m - 2) * 16384))
                           + p * 16 * 128;
        float* dst = WT + m * 16384 + p * 16;
        __shared__ float lds[16][129];
        #pragma unroll
        for (int it = 0; it < 8; ++it) {
            int lin = it * 256 + t;
            int o = lin >> 7, k = lin & 127;
            lds[o][k] = src[lin];
        }
        __syncthreads();
        #pragma unroll
        for (int it = 0; it < 8; ++it) {
            int lin = it * 256 + t;
            int k = lin >> 4, oo = lin & 15;
            dst[k * 128 + oo] = lds[oo][k];
        }
        return;
    }

    int base = (blockIdx.x - 32) * 64;
    __shared__ int stypes[64];
    int myti = 0;
    if (t < 64) {
        int row = base + t;
        int ti = sat[row]; ti = min(max(ti, 0), NTYPES - 1);
        stypes[t] = ti; myti = ti;
        const float* rp = x_now + (size_t)row * DD;
        float f0 = rp[0], f2 = rp[1], f3 = rp[2];
        float nrm = fmaxf(sqrtf(2.f * f0 * f0 + f2 * f2 + f3 * f3), 1e-12f);
        float inv = 1.f / nrm;
        fn[row] = make_float4(f0 * inv, f0 * inv, f2 * inv, f3 * inv);
    }
    #pragma unroll
    for (int it = 0; it < 32; ++it) {
        int lin = it * 256 + t;
        int rl = lin >> 7, col = lin & 127;
        int row = base + rl;
        const float* rp = x_now + (size_t)row * DD;
        float v = (col == 0) ? rp[0] : rp[col - 1];
        x[(size_t)row * HH + col] = v;
        xbf[(size_t)row * HH + col] = f2bf(v);
    }
    __syncthreads();
    if (t < 64) {
        #pragma unroll
        for (int tt = 0; tt < NTYPES; ++tt) {
            unsigned long long m = __ballot(myti == tt);
            if (t == 0) {
                int c = __popcll(m);
                if (c) atomicAdd(&cnt[tt], c);
            }
        }
    }
    if (t < 128) {
        float acc[NTYPES] = {0.f, 0.f, 0.f, 0.f, 0.f, 0.f};
        for (int r = 0; r < 64; ++r) {
            float v = x[(size_t)(base + r) * HH + t];
            int tt = stypes[r];
            #pragma unroll
            for (int q = 0; q < NTYPES; ++q) acc[q] += (tt == q) ? v : 0.f;
        }
        #pragma unroll
        for (int q = 0; q < NTYPES; ++q) atomicAdd(&S0[q * HH + t], acc[q]);
    }
}

// ---------------------------------------------------------------------------
// Kernel B: cross-type cosine adjacency bitmask + degree, MROW rows/block.
// Bit layout: word w (0..127) of row i, bit b (0..31) <-> j = b*128 + w.
// ---------------------------------------------------------------------------
__global__ __launch_bounds__(HH) void build_mask(
    const float4* __restrict__ fn, const int* __restrict__ sat,
    const int* __restrict__ cnt, unsigned* __restrict__ mask,
    float* __restrict__ deg)
{
    int i0 = blockIdx.x * MROW;
    int w = threadIdx.x;  // 0..127
    float4 fi[MROW];
    int ti[MROW];
    #pragma unroll
    for (int r = 0; r < MROW; ++r) {
        fi[r] = fn[i0 + r];
        int t = sat[i0 + r];
        ti[r] = min(max(t, 0), NTYPES - 1);
    }
    unsigned word[MROW] = {0, 0, 0, 0};
    for (int b = 0; b < 32; ++b) {
        int j = b * 128 + w;
        float4 fj = fn[j];
        int tj = sat[j];
        #pragma unroll
        for (int r = 0; r < MROW; ++r) {
            float dot = fi[r].x * fj.x + fi[r].y * fj.y
                      + fi[r].z * fj.z + fi[r].w * fj.w;
            if (tj != ti[r] && dot > SIM_THRESH) word[r] |= (1u << b);
        }
    }
    int pcs[MROW];
    #pragma unroll
    for (int r = 0; r < MROW; ++r) {
        mask[(size_t)(i0 + r) * 128 + w] = word[r];
        pcs[r] = __popc(word[r]);
    }
    int lane = w & 63, wv = w >> 6;
    for (int s = 32; s; s >>= 1) {
        #pragma unroll
        for (int r = 0; r < MROW; ++r) pcs[r] += __shfl_down(pcs[r], s);
    }
    __shared__ int wt[2][MROW];
    if (lane == 0) {
        #pragma unroll
        for (int r = 0; r < MROW; ++r) wt[wv][r] = pcs[r];
    }
    __syncthreads();
    if (w < MROW) {
        int r = w;
        float d = (float)(cnt[ti[r]] - 1 + wt[0][r] + wt[1][r]);
        deg[i0 + r] = fmaxf(d, 1.0f);
    }
}

// ---------------------------------------------------------------------------
// Kernel D v8: TWO waves per row; gather reads the BF16 replica.
// R7/R8 showed time tracks gather-instruction count (~73 cyc each, wave
// count irrelevant) -> bf16 rows (256 B) pack 4 neighbor rows per wave
// instruction (uint4 = 8 bf16/lane, 16 lanes/row): instructions, 128B
// lines, and bytes all halve vs fp32.
// lane = (q, c): q = lane>>4 neighbor slot 0..3, c = lane&15 -> 8 cols.
// MODE 1: epilogue writes hout fp32 + bf16 replica + next-layer type-sums.
// MODE 2: epilogue writes hout fp32 + BN stats.
// ---------------------------------------------------------------------------
template <int MODE>
__global__ __launch_bounds__(256, 8) void layer_kernel(
    const float* __restrict__ h, const ushortT* __restrict__ hbf,
    const unsigned* __restrict__ mask,
    const float* __restrict__ deg, const float* __restrict__ S, int nrepS,
    const int* __restrict__ sat,
    const float* __restrict__ WTl, const float* __restrict__ bl,
    const float* __restrict__ WTr, float* __restrict__ hout,
    ushortT* __restrict__ houtbf,
    float* __restrict__ acc0, float* __restrict__ acc1)
{
    int t = threadIdx.x;
    int wv = t >> 6;          // wave id 0..3
    int lane = t & 63;
    int r  = wv >> 1;         // row slot 0..1
    int hf = wv & 1;          // half 0..1
    int i0 = blockIdx.x * 2;
    int i = i0 + r;

    __shared__ ushortT list[4][LMAXH];                   // 2 KB
    __shared__ __align__(16) float hs[2][HH];            // 1 KB
    __shared__ __align__(16) float ms[2][HH];            // 1 KB
    __shared__ __align__(16) float part[4][HH];          // 2 KB (reused for out)
    __shared__ int tarr[2];

    if (t < 2) {
        int tt = sat[i0 + t];
        tarr[t] = min(max(tt, 0), NTYPES - 1);
    }

    // ---- decode: wave (r,hf) owns mask words hf*64+lane of row i ----
    int widx = hf * 64 + lane;
    unsigned word = mask[(size_t)i * 128 + widx];
    int pc = __popc(word);
    int x = pc;
    for (int s = 1; s < 64; s <<= 1) {
        int v = __shfl_up(x, s);
        if (lane >= s) x += v;
    }
    int ncnt = __shfl(x, 63);
    int ofs = x - pc;
    unsigned ww = word;
    while (ww) {
        int b = __ffs(ww) - 1; ww &= ww - 1;
        list[wv][ofs++] = (ushortT)(b * 128 + widx);
    }
    if (hf == 0)
        ((float2*)hs[r])[lane] = ((const float2*)(h + (size_t)i * HH))[lane];

    // ---- gather own half-list from bf16 replica: 4 rows/instr, 6 deep ----
    int q = lane >> 4;        // 0..3 neighbor slot
    int c = lane & 15;        // 0..15 -> columns 8c..8c+7
    const uint4* __restrict__ hb4 = (const uint4*)hbf;
    float acc[8] = {0.f, 0.f, 0.f, 0.f, 0.f, 0.f, 0.f, 0.f};
#define BFACC(vv)                                                         \
    {                                                                     \
        acc[0] += __uint_as_float((vv).x << 16);                          \
        acc[1] += __uint_as_float((vv).x & 0xffff0000u);                  \
        acc[2] += __uint_as_float((vv).y << 16);                          \
        acc[3] += __uint_as_float((vv).y & 0xffff0000u);                  \
        acc[4] += __uint_as_float((vv).z << 16);                          \
        acc[5] += __uint_as_float((vv).z & 0xffff0000u);                  \
        acc[6] += __uint_as_float((vv).w << 16);                          \
        acc[7] += __uint_as_float((vv).w & 0xffff0000u);                  \
    }
    int g = 0;
    for (; g + 24 <= ncnt; g += 24) {
        int j0 = list[wv][g + q];
        int j1 = list[wv][g + 4 + q];
        int j2 = list[wv][g + 8 + q];
        int j3 = list[wv][g + 12 + q];
        int j4 = list[wv][g + 16 + q];
        int j5 = list[wv][g + 20 + q];
        uint4 v0 = hb4[j0 * 16 + c];
        uint4 v1 = hb4[j1 * 16 + c];
        uint4 v2 = hb4[j2 * 16 + c];
        uint4 v3 = hb4[j3 * 16 + c];
        uint4 v4 = hb4[j4 * 16 + c];
        uint4 v5 = hb4[j5 * 16 + c];
        BFACC(v0); BFACC(v1); BFACC(v2); BFACC(v3); BFACC(v4); BFACC(v5);
    }
    for (; g + 4 <= ncnt; g += 4) {
        int j0 = list[wv][g + q];
        uint4 v0 = hb4[j0 * 16 + c];
        BFACC(v0);
    }
    if (q < ncnt - g) {
        int j0 = list[wv][g + q];
        uint4 v0 = hb4[j0 * 16 + c];
        BFACC(v0);
    }
#undef BFACC
    // reduce across the 4 neighbor slots (q): lanes 0..15 end with the sum
    #pragma unroll
    for (int d = 0; d < 8; ++d) {
        acc[d] += __shfl_down(acc[d], 32);
        acc[d] += __shfl_down(acc[d], 16);
    }
    if (lane < 16) {
        float4 p0 = {acc[0], acc[1], acc[2], acc[3]};
        float4 p1 = {acc[4], acc[5], acc[6], acc[7]};
        ((float4*)part[wv])[c * 2] = p0;
        ((float4*)part[wv])[c * 2 + 1] = p1;
    }
    __syncthreads();   // barrier 1: partials + tarr ready

    // ---- combine halves + m (hf==0 wave, lanes 0..31; cc = float4 chunk) ----
    if (hf == 0 && lane < 32) {
        int cc = lane;
        float4 p0 = ((const float4*)part[wv])[cc];
        float4 p1 = ((const float4*)part[wv + 1])[cc];
        int ti = tarr[r];
        float rdeg = 1.f / deg[i];
        float4 hv = ((const float4*)hs[r])[cc];
        float4 Sv = {0.f, 0.f, 0.f, 0.f};
        for (int rr = 0; rr < nrepS; ++rr) {
            float4 sv = ((const float4*)S)[(rr * NTYPES + ti) * 32 + cc];
            Sv.x += sv.x; Sv.y += sv.y; Sv.z += sv.z; Sv.w += sv.w;
        }
        float4 m;
        m.x = (Sv.x - hv.x + p0.x + p1.x) * rdeg;
        m.y = (Sv.y - hv.y + p0.y + p1.y) * rdeg;
        m.z = (Sv.z - hv.z + p0.z + p1.z) * rdeg;
        m.w = (Sv.w - hv.w + p0.w + p1.w) * rdeg;
        ((float4*)ms[r])[cc] = m;
    }
    __syncthreads();   // barrier 2: ms ready; part free for reuse

    // ---- matmul: wave (r,hf) computes outputs c4 = hf*16+(lane&15);
    //      4-way k-split in wave: kh = lane>>4, k = kh*32+kk ----
    int c4 = hf * 16 + (lane & 15);
    int kh = lane >> 4;
    const float4* __restrict__ WTl4 = (const float4*)WTl;
    const float4* __restrict__ WTr4 = (const float4*)WTr;
    const float* msr = ms[r];
    const float* hsr = hs[r];
    int kbase = kh * 32;
    float4 macc = {0.f, 0.f, 0.f, 0.f};
    #pragma unroll 4
    for (int kk = 0; kk < 32; ++kk) {
        int k = kbase + kk;
        float4 wl = WTl4[k * 32 + c4];
        float4 wr = WTr4[k * 32 + c4];
        float mk = msr[k];
        float hk = hsr[k];
        macc.x += mk * wl.x + hk * wr.x;
        macc.y += mk * wl.y + hk * wr.y;
        macc.z += mk * wl.z + hk * wr.z;
        macc.w += mk * wl.w + hk * wr.w;
    }
    macc.x += __shfl_down(macc.x, 32);
    macc.y += __shfl_down(macc.y, 32);
    macc.z += __shfl_down(macc.z, 32);
    macc.w += __shfl_down(macc.w, 32);
    macc.x += __shfl_down(macc.x, 16);
    macc.y += __shfl_down(macc.y, 16);
    macc.z += __shfl_down(macc.z, 16);
    macc.w += __shfl_down(macc.w, 16);
    if (lane < 16) {
        float4 bv = ((const float4*)bl)[c4];
        float4 o4;
        o4.x = fmaxf(macc.x + bv.x, 0.f);
        o4.y = fmaxf(macc.y + bv.y, 0.f);
        o4.z = fmaxf(macc.z + bv.z, 0.f);
        o4.w = fmaxf(macc.w + bv.w, 0.f);
        ((float4*)(hout + (size_t)i * HH))[c4] = o4;
        if (MODE == 1) {
            ushort4 b4;
            b4.x = f2bf(o4.x); b4.y = f2bf(o4.y);
            b4.z = f2bf(o4.z); b4.w = f2bf(o4.w);
            ((ushort4*)(houtbf + (size_t)i * HH))[c4] = b4;
        }
        ((float4*)part[r])[c4] = o4;    // stage for fused epilogue
    }
    __syncthreads();   // barrier 3: staged outputs ready

    // ---- fused epilogue ----
    int rep = blockIdx.x & (NREP - 1);
    if (MODE == 1) {
        if (t < HH) {
            #pragma unroll
            for (int rr = 0; rr < 2; ++rr)
                atomicAdd(&acc0[(rep * NTYPES + tarr[rr]) * HH + t], part[rr][t]);
        }
    } else {
        if (t < HH) {
            float s = 0.f, s2 = 0.f;
            #pragma unroll
            for (int rr = 0; rr < 2; ++rr) {
                float v = part[rr][t];
                s += v; s2 += v * v;
            }
            atomicAdd(&acc0[rep * HH + t], s);
            atomicAdd(&acc1[rep * HH + t], s2);
        }
    }
}

// ---------------------------------------------------------------------------
// Kernel F: BN apply + head, one wave per row; sums the NREP stat replicas.
// ---------------------------------------------------------------------------
__global__ __launch_bounds__(256) void finalize(
    const float* __restrict__ h, const float* __restrict__ musum8,
    const float* __restrict__ varsum8, const float* __restrict__ gamma,
    const float* __restrict__ beta, const float* __restrict__ Wo,
    const float* __restrict__ bo, float* __restrict__ out_h,
    float* __restrict__ out_o)
{
    int t = threadIdx.x;
    int wv = t >> 6;
    int lane = t & 63;
    int i = blockIdx.x * 4 + wv;

    float2 mus = {0.f, 0.f}, vas = {0.f, 0.f};
    #pragma unroll
    for (int r = 0; r < NREP; ++r) {
        float2 a = ((const float2*)(musum8 + r * HH))[lane];
        float2 b = ((const float2*)(varsum8 + r * HH))[lane];
        mus.x += a.x; mus.y += a.y;
        vas.x += b.x; vas.y += b.y;
    }
    float2 ga  = ((const float2*)gamma)[lane];
    float2 be  = ((const float2*)beta)[lane];
    float mu0 = mus.x * (1.f / NN), mu1 = mus.y * (1.f / NN);
    float v0 = vas.x * (1.f / NN) - mu0 * mu0;
    float v1 = vas.y * (1.f / NN) - mu1 * mu1;
    float sc0 = ga.x / sqrtf(v0 + BN_EPS), sc1 = ga.y / sqrtf(v1 + BN_EPS);
    float sh0 = be.x - mu0 * sc0, sh1 = be.y - mu1 * sc1;

    float2 hv = ((const float2*)(h + (size_t)i * HH))[lane];
    float2 hb;
    hb.x = hv.x * sc0 + sh0;
    hb.y = hv.y * sc1 + sh1;
    ((float2*)(out_h + (size_t)i * HH))[lane] = hb;

    float2 w0 = ((const float2*)Wo)[lane];
    float2 w1 = ((const float2*)(Wo + HH))[lane];
    float2 w2 = ((const float2*)(Wo + 2 * HH))[lane];
    float p0 = hb.x * w0.x + hb.y * w0.y;
    float p1 = hb.x * w1.x + hb.y * w1.y;
    float p2 = hb.x * w2.x + hb.y * w2.y;
    for (int s = 32; s; s >>= 1) {
        p0 += __shfl_down(p0, s);
        p1 += __shfl_down(p1, s);
        p2 += __shfl_down(p2, s);
    }
    if (lane == 0) {
        out_o[(size_t)i * OUTD + 0] = p0 + bo[0];
        out_o[(size_t)i * OUTD + 1] = p1 + bo[1];
        out_o[(size_t)i * OUTD + 2] = p2 + bo[2];
    }
}

// ---------------------------------------------------------------------------
extern "C" void kernel_launch(void* const* d_in, const int* in_sizes, int n_in,
                              void* d_out, int out_size, void* d_ws, size_t ws_size,
                              hipStream_t stream)
{
    (void)in_sizes; (void)n_in; (void)out_size; (void)ws_size;
    const float* x_now = (const float*)d_in[0];
    const int*   sat   = (const int*)d_in[1];
    const float* Wl    = (const float*)d_in[2];
    const float* bl    = (const float*)d_in[3];
    const float* Wr    = (const float*)d_in[4];
    const float* gamma = (const float*)d_in[5];
    const float* beta  = (const float*)d_in[6];
    const float* Wo    = (const float*)d_in[7];
    const float* bo    = (const float*)d_in[8];

    float* ws = (float*)d_ws;
    float* x0 = ws;                          // 524288 floats
    float* h1 = x0 + (size_t)NN * HH;        // 524288
    float* h2 = h1 + (size_t)NN * HH;        // 524288
    float* WT = h2 + (size_t)NN * HH;        // 65536 (Wl0,Wl1,Wr0,Wr1 transposed)
    ushortT* x0bf = (ushortT*)(WT + 65536);            // 524288 u16 = 1 MB
    ushortT* h1bf = x0bf + (size_t)NN * HH;            // 524288 u16
    float4* fn = (float4*)(h1bf + (size_t)NN * HH);    // 4096 float4
    unsigned* mask = (unsigned*)((float*)fn + 4 * NN); // 524288 words
    float* deg = (float*)(mask + (size_t)NN * 128);    // 4096
    // ---- zeroed accumulator region (one contiguous memset) ----
    int*   cnt   = (int*)(deg + NN);                   // 8
    float* S0    = (float*)(cnt + 8);                  // 768
    float* S1rep = S0 + NTYPES * HH;                   // NREP*768 = 6144
    float* mu8   = S1rep + NREP * NTYPES * HH;         // NREP*128 = 1024
    float* var8  = mu8 + NREP * HH;                    // 1024

    size_t zero_bytes = (8 + NTYPES * HH + NREP * NTYPES * HH + 2 * NREP * HH)
                        * sizeof(float);
    hipMemsetAsync(cnt, 0, zero_bytes, stream);

    prep<<<96, 256, 0, stream>>>(x_now, sat, Wl, Wr, WT, x0, x0bf, fn, cnt, S0);
    build_mask<<<NN / MROW, HH, 0, stream>>>(fn, sat, cnt, mask, deg);

    layer_kernel<1><<<NN / 2, 256, 0, stream>>>(
        x0, x0bf, mask, deg, S0, 1, sat, WT, bl, WT + 32768, h1, h1bf,
        S1rep, nullptr);
    layer_kernel<2><<<NN / 2, 256, 0, stream>>>(
        h1, h1bf, mask, deg, S1rep, NREP, sat, WT + 16384, bl + HH, WT + 49152,
        h2, nullptr, mu8, var8);

    finalize<<<NN / 4, 256, 0, stream>>>(h2, mu8, var8, gamma, beta, Wo, bo,
                                         (float*)d_out, (float*)d_out + (size_t)NN * HH);
}

// Round 10
// 156.801 us; speedup vs baseline: 1.3135x; 1.0207x over previous
//
#include <hip/hip_runtime.h>
#include <hip/hip_bf16.h>
#include <math.h>

#define NN 4096
#define DD 127
#define HH 128
#define OUTD 3
#define NTYPES 6
#define SIM_THRESH 0.9f
#define BN_EPS 1e-5f
#define MROW 4    // rows per block in build_mask
#define NREP 8    // accumulator replicas (kills atomic same-address serialization)
// Half-row neighbor list capacity. Half-degree is Binomial(~1706, 0.05):
// mean 85, sigma 9 -> 256 = 19-sigma bound.
#define LMAXH 256

typedef unsigned short ushortT;

// round-to-nearest-even fp32 -> bf16 (bit pattern)
static __device__ inline ushortT f2bf(float f) {
    unsigned u = __float_as_uint(f);
    unsigned r = (u + 0x7fffu + ((u >> 16) & 1u)) >> 16;
    return (ushortT)r;
}

// ---------------------------------------------------------------------------
// Kernel P v3: blocks 0..31 transpose weights; blocks 32..287 each own a
// 16-row strip (R9's 64 strip-blocks = 0.25 blocks/CU left the chip idle
// during prep). cnt and S0 use NREP replicas (rep = strip & 7) so the 4x
// more blocks don't serialize on the same atomic addresses.
// ---------------------------------------------------------------------------
__global__ __launch_bounds__(256) void prep(
    const float* __restrict__ x_now, const int* __restrict__ sat,
    const float* __restrict__ Wl, const float* __restrict__ Wr,
    float* __restrict__ WT, float* __restrict__ x, ushortT* __restrict__ xbf,
    float4* __restrict__ fn, int* __restrict__ cnt, float* __restrict__ S0rep)
{
    int t = threadIdx.x;
    if (blockIdx.x < 32) {
        int m = blockIdx.x >> 3;       // 0:Wl0 1:Wl1 2:Wr0 3:Wr1
        int p = blockIdx.x & 7;        // 16-row tile
        const float* src = ((m < 2) ? (Wl + m * 16384) : (Wr + (m - 2) * 16384))
                           + p * 16 * 128;
        float* dst = WT + m * 16384 + p * 16;
        __shared__ float lds[16][129];
        #pragma unroll
        for (int it = 0; it < 8; ++it) {
            int lin = it * 256 + t;
            int o = lin >> 7, k = lin & 127;
            lds[o][k] = src[lin];
        }
        __syncthreads();
        #pragma unroll
        for (int it = 0; it < 8; ++it) {
            int lin = it * 256 + t;
            int k = lin >> 4, oo = lin & 15;
            dst[k * 128 + oo] = lds[oo][k];
        }
        return;
    }

    int sb = blockIdx.x - 32;          // strip 0..255
    int base = sb * 16;
    int rep = sb & (NREP - 1);
    __shared__ int stypes[16];
    int myti = -1;
    if (t < 16) {
        int row = base + t;
        int ti = sat[row]; ti = min(max(ti, 0), NTYPES - 1);
        stypes[t] = ti; myti = ti;
        const float* rp = x_now + (size_t)row * DD;
        float f0 = rp[0], f2 = rp[1], f3 = rp[2];
        float nrm = fmaxf(sqrtf(2.f * f0 * f0 + f2 * f2 + f3 * f3), 1e-12f);
        float inv = 1.f / nrm;
        fn[row] = make_float4(f0 * inv, f0 * inv, f2 * inv, f3 * inv);
    }
    #pragma unroll
    for (int it = 0; it < 8; ++it) {
        int lin = it * 256 + t;        // 0..2047
        int rl = lin >> 7, col = lin & 127;
        int row = base + rl;
        const float* rp = x_now + (size_t)row * DD;
        float v = (col == 0) ? rp[0] : rp[col - 1];
        x[(size_t)row * HH + col] = v;
        xbf[(size_t)row * HH + col] = f2bf(v);
    }
    __syncthreads();
    if (t < 64) {
        // wave-0 ballot histogram (lanes >=16 have myti=-1)
        #pragma unroll
        for (int tt = 0; tt < NTYPES; ++tt) {
            unsigned long long m = __ballot(myti == tt);
            if (t == 0) {
                int c = __popcll(m);
                if (c) atomicAdd(&cnt[rep * NTYPES + tt], c);
            }
        }
    }
    if (t < 128) {
        float acc[NTYPES] = {0.f, 0.f, 0.f, 0.f, 0.f, 0.f};
        for (int r = 0; r < 16; ++r) {
            float v = x[(size_t)(base + r) * HH + t];   // L1/L2 hit (just wrote)
            int tt = stypes[r];
            #pragma unroll
            for (int q = 0; q < NTYPES; ++q) acc[q] += (tt == q) ? v : 0.f;
        }
        #pragma unroll
        for (int q = 0; q < NTYPES; ++q)
            atomicAdd(&S0rep[(rep * NTYPES + q) * HH + t], acc[q]);
    }
}

// ---------------------------------------------------------------------------
// Kernel B v3: 256 threads; the 32-iteration b-loop is split across two
// thread-halves (serial depth 16, waves/CU 8 -> 16; R9's build_mask was
// latency-bound on the fj-load chain). Halves OR-combined through LDS.
// Bit layout: word w (0..127) of row i, bit b (0..31) <-> j = b*128 + w.
// cnt has NREP replicas (summed here for deg).
// ---------------------------------------------------------------------------
__global__ __launch_bounds__(256) void build_mask(
    const float4* __restrict__ fn, const int* __restrict__ sat,
    const int* __restrict__ cnt, unsigned* __restrict__ mask,
    float* __restrict__ deg)
{
    int i0 = blockIdx.x * MROW;
    int t = threadIdx.x;
    int w = t & 127;
    int half = t >> 7;
    float4 fi[MROW];
    int ti[MROW];
    #pragma unroll
    for (int r = 0; r < MROW; ++r) {
        fi[r] = fn[i0 + r];
        int tt = sat[i0 + r];
        ti[r] = min(max(tt, 0), NTYPES - 1);
    }
    unsigned word[MROW] = {0, 0, 0, 0};
    int bbase = half * 16;
    for (int bb = 0; bb < 16; ++bb) {
        int b = bbase + bb;
        int j = b * 128 + w;
        float4 fj = fn[j];
        int tj = sat[j];
        #pragma unroll
        for (int r = 0; r < MROW; ++r) {
            float dot = fi[r].x * fj.x + fi[r].y * fj.y
                      + fi[r].z * fj.z + fi[r].w * fj.w;
            if (tj != ti[r] && dot > SIM_THRESH) word[r] |= (1u << b);
        }
    }
    __shared__ unsigned wpart[MROW][128];
    if (half == 1) {
        #pragma unroll
        for (int r = 0; r < MROW; ++r) wpart[r][w] = word[r];
    }
    __syncthreads();
    __shared__ int wt[2][MROW];
    if (half == 0) {
        int pcs[MROW];
        #pragma unroll
        for (int r = 0; r < MROW; ++r) {
            unsigned full = word[r] | wpart[r][w];
            mask[(size_t)(i0 + r) * 128 + w] = full;
            pcs[r] = __popc(full);
        }
        int lane = w & 63, wv2 = w >> 6;
        for (int s = 32; s; s >>= 1) {
            #pragma unroll
            for (int r = 0; r < MROW; ++r) pcs[r] += __shfl_down(pcs[r], s);
        }
        if (lane == 0) {
            #pragma unroll
            for (int r = 0; r < MROW; ++r) wt[wv2][r] = pcs[r];
        }
    }
    __syncthreads();
    if (t < MROW) {
        int r = t;
        int ctot = 0;
        #pragma unroll
        for (int rr = 0; rr < NREP; ++rr) ctot += cnt[rr * NTYPES + ti[r]];
        float d = (float)(ctot - 1 + wt[0][r] + wt[1][r]);
        deg[i0 + r] = fmaxf(d, 1.0f);
    }
}

// ---------------------------------------------------------------------------
// Kernel D v8 (unchanged from R9): TWO waves per row; bf16 gather replica.
// ---------------------------------------------------------------------------
template <int MODE>
__global__ __launch_bounds__(256, 8) void layer_kernel(
    const float* __restrict__ h, const ushortT* __restrict__ hbf,
    const unsigned* __restrict__ mask,
    const float* __restrict__ deg, const float* __restrict__ S, int nrepS,
    const int* __restrict__ sat,
    const float* __restrict__ WTl, const float* __restrict__ bl,
    const float* __restrict__ WTr, float* __restrict__ hout,
    ushortT* __restrict__ houtbf,
    float* __restrict__ acc0, float* __restrict__ acc1)
{
    int t = threadIdx.x;
    int wv = t >> 6;          // wave id 0..3
    int lane = t & 63;
    int r  = wv >> 1;         // row slot 0..1
    int hf = wv & 1;          // half 0..1
    int i0 = blockIdx.x * 2;
    int i = i0 + r;

    __shared__ ushortT list[4][LMAXH];                   // 2 KB
    __shared__ __align__(16) float hs[2][HH];            // 1 KB
    __shared__ __align__(16) float ms[2][HH];            // 1 KB
    __shared__ __align__(16) float part[4][HH];          // 2 KB (reused for out)
    __shared__ int tarr[2];

    if (t < 2) {
        int tt = sat[i0 + t];
        tarr[t] = min(max(tt, 0), NTYPES - 1);
    }

    // ---- decode: wave (r,hf) owns mask words hf*64+lane of row i ----
    int widx = hf * 64 + lane;
    unsigned word = mask[(size_t)i * 128 + widx];
    int pc = __popc(word);
    int x = pc;
    for (int s = 1; s < 64; s <<= 1) {
        int v = __shfl_up(x, s);
        if (lane >= s) x += v;
    }
    int ncnt = __shfl(x, 63);
    int ofs = x - pc;
    unsigned ww = word;
    while (ww) {
        int b = __ffs(ww) - 1; ww &= ww - 1;
        list[wv][ofs++] = (ushortT)(b * 128 + widx);
    }
    if (hf == 0)
        ((float2*)hs[r])[lane] = ((const float2*)(h + (size_t)i * HH))[lane];

    // ---- gather own half-list from bf16 replica: 4 rows/instr, 6 deep ----
    int q = lane >> 4;        // 0..3 neighbor slot
    int c = lane & 15;        // 0..15 -> columns 8c..8c+7
    const uint4* __restrict__ hb4 = (const uint4*)hbf;
    float acc[8] = {0.f, 0.f, 0.f, 0.f, 0.f, 0.f, 0.f, 0.f};
#define BFACC(vv)                                                         \
    {                                                                     \
        acc[0] += __uint_as_float((vv).x << 16);                          \
        acc[1] += __uint_as_float((vv).x & 0xffff0000u);                  \
        acc[2] += __uint_as_float((vv).y << 16);                          \
        acc[3] += __uint_as_float((vv).y & 0xffff0000u);                  \
        acc[4] += __uint_as_float((vv).z << 16);                          \
        acc[5] += __uint_as_float((vv).z & 0xffff0000u);                  \
        acc[6] += __uint_as_float((vv).w << 16);                          \
        acc[7] += __uint_as_float((vv).w & 0xffff0000u);                  \
    }
    int g = 0;
    for (; g + 24 <= ncnt; g += 24) {
        int j0 = list[wv][g + q];
        int j1 = list[wv][g + 4 + q];
        int j2 = list[wv][g + 8 + q];
        int j3 = list[wv][g + 12 + q];
        int j4 = list[wv][g + 16 + q];
        int j5 = list[wv][g + 20 + q];
        uint4 v0 = hb4[j0 * 16 + c];
        uint4 v1 = hb4[j1 * 16 + c];
        uint4 v2 = hb4[j2 * 16 + c];
        uint4 v3 = hb4[j3 * 16 + c];
        uint4 v4 = hb4[j4 * 16 + c];
        uint4 v5 = hb4[j5 * 16 + c];
        BFACC(v0); BFACC(v1); BFACC(v2); BFACC(v3); BFACC(v4); BFACC(v5);
    }
    for (; g + 4 <= ncnt; g += 4) {
        int j0 = list[wv][g + q];
        uint4 v0 = hb4[j0 * 16 + c];
        BFACC(v0);
    }
    if (q < ncnt - g) {
        int j0 = list[wv][g + q];
        uint4 v0 = hb4[j0 * 16 + c];
        BFACC(v0);
    }
#undef BFACC
    #pragma unroll
    for (int d = 0; d < 8; ++d) {
        acc[d] += __shfl_down(acc[d], 32);
        acc[d] += __shfl_down(acc[d], 16);
    }
    if (lane < 16) {
        float4 p0 = {acc[0], acc[1], acc[2], acc[3]};
        float4 p1 = {acc[4], acc[5], acc[6], acc[7]};
        ((float4*)part[wv])[c * 2] = p0;
        ((float4*)part[wv])[c * 2 + 1] = p1;
    }
    __syncthreads();   // barrier 1: partials + tarr ready

    if (hf == 0 && lane < 32) {
        int cc = lane;
        float4 p0 = ((const float4*)part[wv])[cc];
        float4 p1 = ((const float4*)part[wv + 1])[cc];
        int ti = tarr[r];
        float rdeg = 1.f / deg[i];
        float4 hv = ((const float4*)hs[r])[cc];
        float4 Sv = {0.f, 0.f, 0.f, 0.f};
        for (int rr = 0; rr < nrepS; ++rr) {
            float4 sv = ((const float4*)S)[(rr * NTYPES + ti) * 32 + cc];
            Sv.x += sv.x; Sv.y += sv.y; Sv.z += sv.z; Sv.w += sv.w;
        }
        float4 m;
        m.x = (Sv.x - hv.x + p0.x + p1.x) * rdeg;
        m.y = (Sv.y - hv.y + p0.y + p1.y) * rdeg;
        m.z = (Sv.z - hv.z + p0.z + p1.z) * rdeg;
        m.w = (Sv.w - hv.w + p0.w + p1.w) * rdeg;
        ((float4*)ms[r])[cc] = m;
    }
    __syncthreads();   // barrier 2: ms ready; part free for reuse

    int c4 = hf * 16 + (lane & 15);
    int kh = lane >> 4;
    const float4* __restrict__ WTl4 = (const float4*)WTl;
    const float4* __restrict__ WTr4 = (const float4*)WTr;
    const float* msr = ms[r];
    const float* hsr = hs[r];
    int kbase = kh * 32;
    float4 macc = {0.f, 0.f, 0.f, 0.f};
    #pragma unroll 4
    for (int kk = 0; kk < 32; ++kk) {
        int k = kbase + kk;
        float4 wl = WTl4[k * 32 + c4];
        float4 wr = WTr4[k * 32 + c4];
        float mk = msr[k];
        float hk = hsr[k];
        macc.x += mk * wl.x + hk * wr.x;
        macc.y += mk * wl.y + hk * wr.y;
        macc.z += mk * wl.z + hk * wr.z;
        macc.w += mk * wl.w + hk * wr.w;
    }
    macc.x += __shfl_down(macc.x, 32);
    macc.y += __shfl_down(macc.y, 32);
    macc.z += __shfl_down(macc.z, 32);
    macc.w += __shfl_down(macc.w, 32);
    macc.x += __shfl_down(macc.x, 16);
    macc.y += __shfl_down(macc.y, 16);
    macc.z += __shfl_down(macc.z, 16);
    macc.w += __shfl_down(macc.w, 16);
    if (lane < 16) {
        float4 bv = ((const float4*)bl)[c4];
        float4 o4;
        o4.x = fmaxf(macc.x + bv.x, 0.f);
        o4.y = fmaxf(macc.y + bv.y, 0.f);
        o4.z = fmaxf(macc.z + bv.z, 0.f);
        o4.w = fmaxf(macc.w + bv.w, 0.f);
        ((float4*)(hout + (size_t)i * HH))[c4] = o4;
        if (MODE == 1) {
            ushort4 b4;
            b4.x = f2bf(o4.x); b4.y = f2bf(o4.y);
            b4.z = f2bf(o4.z); b4.w = f2bf(o4.w);
            ((ushort4*)(houtbf + (size_t)i * HH))[c4] = b4;
        }
        ((float4*)part[r])[c4] = o4;    // stage for fused epilogue
    }
    __syncthreads();   // barrier 3: staged outputs ready

    int rep = blockIdx.x & (NREP - 1);
    if (MODE == 1) {
        if (t < HH) {
            #pragma unroll
            for (int rr = 0; rr < 2; ++rr)
                atomicAdd(&acc0[(rep * NTYPES + tarr[rr]) * HH + t], part[rr][t]);
        }
    } else {
        if (t < HH) {
            float s = 0.f, s2 = 0.f;
            #pragma unroll
            for (int rr = 0; rr < 2; ++rr) {
                float v = part[rr][t];
                s += v; s2 += v * v;
            }
            atomicAdd(&acc0[rep * HH + t], s);
            atomicAdd(&acc1[rep * HH + t], s2);
        }
    }
}

// ---------------------------------------------------------------------------
// Kernel F: BN apply + head, one wave per row; sums the NREP stat replicas.
// ---------------------------------------------------------------------------
__global__ __launch_bounds__(256) void finalize(
    const float* __restrict__ h, const float* __restrict__ musum8,
    const float* __restrict__ varsum8, const float* __restrict__ gamma,
    const float* __restrict__ beta, const float* __restrict__ Wo,
    const float* __restrict__ bo, float* __restrict__ out_h,
    float* __restrict__ out_o)
{
    int t = threadIdx.x;
    int wv = t >> 6;
    int lane = t & 63;
    int i = blockIdx.x * 4 + wv;

    float2 mus = {0.f, 0.f}, vas = {0.f, 0.f};
    #pragma unroll
    for (int r = 0; r < NREP; ++r) {
        float2 a = ((const float2*)(musum8 + r * HH))[lane];
        float2 b = ((const float2*)(varsum8 + r * HH))[lane];
        mus.x += a.x; mus.y += a.y;
        vas.x += b.x; vas.y += b.y;
    }
    float2 ga  = ((const float2*)gamma)[lane];
    float2 be  = ((const float2*)beta)[lane];
    float mu0 = mus.x * (1.f / NN), mu1 = mus.y * (1.f / NN);
    float v0 = vas.x * (1.f / NN) - mu0 * mu0;
    float v1 = vas.y * (1.f / NN) - mu1 * mu1;
    float sc0 = ga.x / sqrtf(v0 + BN_EPS), sc1 = ga.y / sqrtf(v1 + BN_EPS);
    float sh0 = be.x - mu0 * sc0, sh1 = be.y - mu1 * sc1;

    float2 hv = ((const float2*)(h + (size_t)i * HH))[lane];
    float2 hb;
    hb.x = hv.x * sc0 + sh0;
    hb.y = hv.y * sc1 + sh1;
    ((float2*)(out_h + (size_t)i * HH))[lane] = hb;

    float2 w0 = ((const float2*)Wo)[lane];
    float2 w1 = ((const float2*)(Wo + HH))[lane];
    float2 w2 = ((const float2*)(Wo + 2 * HH))[lane];
    float p0 = hb.x * w0.x + hb.y * w0.y;
    float p1 = hb.x * w1.x + hb.y * w1.y;
    float p2 = hb.x * w2.x + hb.y * w2.y;
    for (int s = 32; s; s >>= 1) {
        p0 += __shfl_down(p0, s);
        p1 += __shfl_down(p1, s);
        p2 += __shfl_down(p2, s);
    }
    if (lane == 0) {
        out_o[(size_t)i * OUTD + 0] = p0 + bo[0];
        out_o[(size_t)i * OUTD + 1] = p1 + bo[1];
        out_o[(size_t)i * OUTD + 2] = p2 + bo[2];
    }
}

// ---------------------------------------------------------------------------
extern "C" void kernel_launch(void* const* d_in, const int* in_sizes, int n_in,
                              void* d_out, int out_size, void* d_ws, size_t ws_size,
                              hipStream_t stream)
{
    (void)in_sizes; (void)n_in; (void)out_size; (void)ws_size;
    const float* x_now = (const float*)d_in[0];
    const int*   sat   = (const int*)d_in[1];
    const float* Wl    = (const float*)d_in[2];
    const float* bl    = (const float*)d_in[3];
    const float* Wr    = (const float*)d_in[4];
    const float* gamma = (const float*)d_in[5];
    const float* beta  = (const float*)d_in[6];
    const float* Wo    = (const float*)d_in[7];
    const float* bo    = (const float*)d_in[8];

    float* ws = (float*)d_ws;
    float* x0 = ws;                          // 524288 floats
    float* h1 = x0 + (size_t)NN * HH;        // 524288
    float* h2 = h1 + (size_t)NN * HH;        // 524288
    float* WT = h2 + (size_t)NN * HH;        // 65536 (Wl0,Wl1,Wr0,Wr1 transposed)
    ushortT* x0bf = (ushortT*)(WT + 65536);            // 524288 u16 = 1 MB
    ushortT* h1bf = x0bf + (size_t)NN * HH;            // 524288 u16
    float4* fn = (float4*)(h1bf + (size_t)NN * HH);    // 4096 float4
    unsigned* mask = (unsigned*)((float*)fn + 4 * NN); // 524288 words
    float* deg = (float*)(mask + (size_t)NN * 128);    // 4096
    // ---- zeroed accumulator region (one contiguous memset) ----
    int*   cnt   = (int*)(deg + NN);                   // NREP*6 (reserve 64)
    float* S0rep = (float*)(cnt + 64);                 // NREP*768 = 6144
    float* S1rep = S0rep + NREP * NTYPES * HH;         // 6144
    float* mu8   = S1rep + NREP * NTYPES * HH;         // 1024
    float* var8  = mu8 + NREP * HH;                    // 1024

    size_t zero_bytes = (64 + 2 * NREP * NTYPES * HH + 2 * NREP * HH)
                        * sizeof(float);
    hipMemsetAsync(cnt, 0, zero_bytes, stream);

    prep<<<288, 256, 0, stream>>>(x_now, sat, Wl, Wr, WT, x0, x0bf, fn, cnt,
                                  S0rep);
    build_mask<<<NN / MROW, 256, 0, stream>>>(fn, sat, cnt, mask, deg);

    layer_kernel<1><<<NN / 2, 256, 0, stream>>>(
        x0, x0bf, mask, deg, S0rep, NREP, sat, WT, bl, WT + 32768, h1, h1bf,
        S1rep, nullptr);
    layer_kernel<2><<<NN / 2, 256, 0, stream>>>(
        h1, h1bf, mask, deg, S1rep, NREP, sat, WT + 16384, bl + HH, WT + 49152,
        h2, nullptr, mu8, var8);

    finalize<<<NN / 4, 256, 0, stream>>>(h2, mu8, var8, gamma, beta, Wo, bo,
                                         (float*)d_out, (float*)d_out + (size_t)NN * HH);
}

// Round 11
// 135.649 us; speedup vs baseline: 1.5184x; 1.1559x over previous
//
#include <hip/hip_runtime.h>
#include <hip/hip_bf16.h>
#include <math.h>

#define NN 4096
#define DD 127
#define HH 128
#define OUTD 3
#define NTYPES 6
#define SIM_THRESH 0.9f
#define BN_EPS 1e-5f
#define MROW 4    // rows per block in build_mask
#define NREP 8    // accumulator replicas
// Half-row neighbor list capacity. Half-degree ~ Binomial(1706, 0.05):
// mean 85, sigma 9 -> 256 = 19-sigma bound.
#define LMAXH 256

typedef unsigned short ushortT;
typedef __attribute__((ext_vector_type(8))) short short8;   // 8 bf16 (4 VGPRs)
typedef __attribute__((ext_vector_type(4))) float f32x4;

// round-to-nearest-even fp32 -> bf16 (bit pattern)
static __device__ inline ushortT f2bf(float f) {
    unsigned u = __float_as_uint(f);
    unsigned r = (u + 0x7fffu + ((u >> 16) & 1u)) >> 16;
    return (ushortT)r;
}

// ---------------------------------------------------------------------------
// Kernel P v4: blocks 0..7 convert W (Wl0,Wl1,Wr0,Wr1) to bf16 (row-major,
// MFMA B-fragment wants k-contiguous rows — no transpose). Blocks 8..263:
// 16-row strips: x fp32 + bf16 replica, fn, histogram, S0 type-sums (NREP
// replicas).
// ---------------------------------------------------------------------------
__global__ __launch_bounds__(256) void prep(
    const float* __restrict__ x_now, const int* __restrict__ sat,
    const float* __restrict__ Wl, const float* __restrict__ Wr,
    ushortT* __restrict__ Wbf, float* __restrict__ x,
    ushortT* __restrict__ xbf, float4* __restrict__ fn,
    int* __restrict__ cnt, float* __restrict__ S0rep)
{
    int t = threadIdx.x;
    if (blockIdx.x < 8) {
        int baseidx = blockIdx.x * 8192;
        #pragma unroll
        for (int it = 0; it < 32; ++it) {
            int idx = baseidx + it * 256 + t;
            float v = (idx < 32768) ? Wl[idx] : Wr[idx - 32768];
            Wbf[idx] = f2bf(v);
        }
        return;
    }

    int sb = blockIdx.x - 8;           // strip 0..255
    int base = sb * 16;
    int rep = sb & (NREP - 1);
    __shared__ int stypes[16];
    int myti = -1;
    if (t < 16) {
        int row = base + t;
        int ti = sat[row]; ti = min(max(ti, 0), NTYPES - 1);
        stypes[t] = ti; myti = ti;
        const float* rp = x_now + (size_t)row * DD;
        float f0 = rp[0], f2 = rp[1], f3 = rp[2];
        float nrm = fmaxf(sqrtf(2.f * f0 * f0 + f2 * f2 + f3 * f3), 1e-12f);
        float inv = 1.f / nrm;
        fn[row] = make_float4(f0 * inv, f0 * inv, f2 * inv, f3 * inv);
    }
    #pragma unroll
    for (int it = 0; it < 8; ++it) {
        int lin = it * 256 + t;        // 0..2047
        int rl = lin >> 7, col = lin & 127;
        int row = base + rl;
        const float* rp = x_now + (size_t)row * DD;
        float v = (col == 0) ? rp[0] : rp[col - 1];
        x[(size_t)row * HH + col] = v;
        xbf[(size_t)row * HH + col] = f2bf(v);
    }
    __syncthreads();
    if (t < 64) {
        #pragma unroll
        for (int tt = 0; tt < NTYPES; ++tt) {
            unsigned long long m = __ballot(myti == tt);
            if (t == 0) {
                int c = __popcll(m);
                if (c) atomicAdd(&cnt[rep * NTYPES + tt], c);
            }
        }
    }
    if (t < 128) {
        float acc[NTYPES] = {0.f, 0.f, 0.f, 0.f, 0.f, 0.f};
        for (int r = 0; r < 16; ++r) {
            float v = x[(size_t)(base + r) * HH + t];
            int tt = stypes[r];
            #pragma unroll
            for (int q = 0; q < NTYPES; ++q) acc[q] += (tt == q) ? v : 0.f;
        }
        #pragma unroll
        for (int q = 0; q < NTYPES; ++q)
            atomicAdd(&S0rep[(rep * NTYPES + q) * HH + t], acc[q]);
    }
}

// ---------------------------------------------------------------------------
// Kernel B v3 (unchanged from R10): bitmask + degree; b-loop split across
// two thread-halves.
// ---------------------------------------------------------------------------
__global__ __launch_bounds__(256) void build_mask(
    const float4* __restrict__ fn, const int* __restrict__ sat,
    const int* __restrict__ cnt, unsigned* __restrict__ mask,
    float* __restrict__ deg)
{
    int i0 = blockIdx.x * MROW;
    int t = threadIdx.x;
    int w = t & 127;
    int half = t >> 7;
    float4 fi[MROW];
    int ti[MROW];
    #pragma unroll
    for (int r = 0; r < MROW; ++r) {
        fi[r] = fn[i0 + r];
        int tt = sat[i0 + r];
        ti[r] = min(max(tt, 0), NTYPES - 1);
    }
    unsigned word[MROW] = {0, 0, 0, 0};
    int bbase = half * 16;
    for (int bb = 0; bb < 16; ++bb) {
        int b = bbase + bb;
        int j = b * 128 + w;
        float4 fj = fn[j];
        int tj = sat[j];
        #pragma unroll
        for (int r = 0; r < MROW; ++r) {
            float dot = fi[r].x * fj.x + fi[r].y * fj.y
                      + fi[r].z * fj.z + fi[r].w * fj.w;
            if (tj != ti[r] && dot > SIM_THRESH) word[r] |= (1u << b);
        }
    }
    __shared__ unsigned wpart[MROW][128];
    if (half == 1) {
        #pragma unroll
        for (int r = 0; r < MROW; ++r) wpart[r][w] = word[r];
    }
    __syncthreads();
    __shared__ int wt[2][MROW];
    if (half == 0) {
        int pcs[MROW];
        #pragma unroll
        for (int r = 0; r < MROW; ++r) {
            unsigned full = word[r] | wpart[r][w];
            mask[(size_t)(i0 + r) * 128 + w] = full;
            pcs[r] = __popc(full);
        }
        int lane = w & 63, wv2 = w >> 6;
        for (int s = 32; s; s >>= 1) {
            #pragma unroll
            for (int r = 0; r < MROW; ++r) pcs[r] += __shfl_down(pcs[r], s);
        }
        if (lane == 0) {
            #pragma unroll
            for (int r = 0; r < MROW; ++r) wt[wv2][r] = pcs[r];
        }
    }
    __syncthreads();
    if (t < MROW) {
        int r = t;
        int ctot = 0;
        #pragma unroll
        for (int rr = 0; rr < NREP; ++rr) ctot += cnt[rr * NTYPES + ti[r]];
        float d = (float)(ctot - 1 + wt[0][r] + wt[1][r]);
        deg[i0 + r] = fmaxf(d, 1.0f);
    }
}

// ---------------------------------------------------------------------------
// Kernel G (gather-only): two waves per row, bf16 gather; writes m as bf16.
// Matmul/epilogue moved to gemm_kernel (R10 model: matmul WT loads were
// 2048 VMEM instr/CU — 3x the gather — every block re-read all of W).
// ---------------------------------------------------------------------------
__global__ __launch_bounds__(256, 8) void gather_kernel(
    const float* __restrict__ h, const ushortT* __restrict__ hbf,
    const unsigned* __restrict__ mask, const float* __restrict__ deg,
    const float* __restrict__ S, const int* __restrict__ sat,
    ushortT* __restrict__ mbf)
{
    int t = threadIdx.x;
    int wv = t >> 6;          // wave id 0..3
    int lane = t & 63;
    int r  = wv >> 1;         // row slot 0..1
    int hf = wv & 1;          // half 0..1
    int i0 = blockIdx.x * 2;
    int i = i0 + r;

    __shared__ ushortT list[4][LMAXH];                   // 2 KB
    __shared__ __align__(16) float hs[2][HH];            // 1 KB
    __shared__ __align__(16) float part[4][HH];          // 2 KB
    __shared__ int tarr[2];

    if (t < 2) {
        int tt = sat[i0 + t];
        tarr[t] = min(max(tt, 0), NTYPES - 1);
    }

    // ---- decode: wave (r,hf) owns mask words hf*64+lane of row i ----
    int widx = hf * 64 + lane;
    unsigned word = mask[(size_t)i * 128 + widx];
    int pc = __popc(word);
    int x = pc;
    for (int s = 1; s < 64; s <<= 1) {
        int v = __shfl_up(x, s);
        if (lane >= s) x += v;
    }
    int ncnt = __shfl(x, 63);
    int ofs = x - pc;
    unsigned ww = word;
    while (ww) {
        int b = __ffs(ww) - 1; ww &= ww - 1;
        list[wv][ofs++] = (ushortT)(b * 128 + widx);
    }
    if (hf == 0)
        ((float2*)hs[r])[lane] = ((const float2*)(h + (size_t)i * HH))[lane];

    // ---- gather own half-list from bf16 rows: 4 rows/instr, 6 deep ----
    int q = lane >> 4;        // 0..3 neighbor slot
    int c = lane & 15;        // 0..15 -> columns 8c..8c+7
    const uint4* __restrict__ hb4 = (const uint4*)hbf;
    float acc[8] = {0.f, 0.f, 0.f, 0.f, 0.f, 0.f, 0.f, 0.f};
#define BFACC(vv)                                                         \
    {                                                                     \
        acc[0] += __uint_as_float((vv).x << 16);                          \
        acc[1] += __uint_as_float((vv).x & 0xffff0000u);                  \
        acc[2] += __uint_as_float((vv).y << 16);                          \
        acc[3] += __uint_as_float((vv).y & 0xffff0000u);                  \
        acc[4] += __uint_as_float((vv).z << 16);                          \
        acc[5] += __uint_as_float((vv).z & 0xffff0000u);                  \
        acc[6] += __uint_as_float((vv).w << 16);                          \
        acc[7] += __uint_as_float((vv).w & 0xffff0000u);                  \
    }
    int g = 0;
    for (; g + 24 <= ncnt; g += 24) {
        int j0 = list[wv][g + q];
        int j1 = list[wv][g + 4 + q];
        int j2 = list[wv][g + 8 + q];
        int j3 = list[wv][g + 12 + q];
        int j4 = list[wv][g + 16 + q];
        int j5 = list[wv][g + 20 + q];
        uint4 v0 = hb4[j0 * 16 + c];
        uint4 v1 = hb4[j1 * 16 + c];
        uint4 v2 = hb4[j2 * 16 + c];
        uint4 v3 = hb4[j3 * 16 + c];
        uint4 v4 = hb4[j4 * 16 + c];
        uint4 v5 = hb4[j5 * 16 + c];
        BFACC(v0); BFACC(v1); BFACC(v2); BFACC(v3); BFACC(v4); BFACC(v5);
    }
    for (; g + 4 <= ncnt; g += 4) {
        int j0 = list[wv][g + q];
        uint4 v0 = hb4[j0 * 16 + c];
        BFACC(v0);
    }
    if (q < ncnt - g) {
        int j0 = list[wv][g + q];
        uint4 v0 = hb4[j0 * 16 + c];
        BFACC(v0);
    }
#undef BFACC
    #pragma unroll
    for (int d = 0; d < 8; ++d) {
        acc[d] += __shfl_down(acc[d], 32);
        acc[d] += __shfl_down(acc[d], 16);
    }
    if (lane < 16) {
        float4 p0 = {acc[0], acc[1], acc[2], acc[3]};
        float4 p1 = {acc[4], acc[5], acc[6], acc[7]};
        ((float4*)part[wv])[c * 2] = p0;
        ((float4*)part[wv])[c * 2 + 1] = p1;
    }
    __syncthreads();   // partials + tarr ready

    if (hf == 0 && lane < 32) {
        int cc = lane;
        float4 p0 = ((const float4*)part[wv])[cc];
        float4 p1 = ((const float4*)part[wv + 1])[cc];
        int ti = tarr[r];
        float rdeg = 1.f / deg[i];
        float4 hv = ((const float4*)hs[r])[cc];
        float4 Sv = {0.f, 0.f, 0.f, 0.f};
        #pragma unroll
        for (int rr = 0; rr < NREP; ++rr) {
            float4 sv = ((const float4*)S)[(rr * NTYPES + ti) * 32 + cc];
            Sv.x += sv.x; Sv.y += sv.y; Sv.z += sv.z; Sv.w += sv.w;
        }
        float4 m;
        m.x = (Sv.x - hv.x + p0.x + p1.x) * rdeg;
        m.y = (Sv.y - hv.y + p0.y + p1.y) * rdeg;
        m.z = (Sv.z - hv.z + p0.z + p1.z) * rdeg;
        m.w = (Sv.w - hv.w + p0.w + p1.w) * rdeg;
        ushort4 mb;
        mb.x = f2bf(m.x); mb.y = f2bf(m.y);
        mb.z = f2bf(m.z); mb.w = f2bf(m.w);
        ((ushort4*)(mbf + (size_t)i * HH))[cc] = mb;
    }
}

// ---------------------------------------------------------------------------
// Kernel M (MFMA GEMM): hout = relu([mbf | hbf] @ [Wl | Wr]^T + bl).
// 256 blocks x 16 rows x 128 outputs, K=256 (128 m + 128 h), bf16 MFMA
// 16x16x32. B-fragment reads W row-major directly (n=lane&15 -> W row,
// k=quad*8+j contiguous). D layout: col=lane&15, row=quad*4+reg (m89).
// Epilogue: bias+relu -> LDS -> coalesced fp32(+bf16) writes + stats.
// MODE 1: next-layer type sums (+ bf16 h replica). MODE 2: BN stats.
// ---------------------------------------------------------------------------
template <int MODE>
__global__ __launch_bounds__(256) void gemm_kernel(
    const ushortT* __restrict__ mbf, const ushortT* __restrict__ hbf,
    const ushortT* __restrict__ Wlbf, const ushortT* __restrict__ Wrbf,
    const float* __restrict__ bl, const int* __restrict__ sat,
    float* __restrict__ hout, ushortT* __restrict__ houtbf,
    float* __restrict__ acc0, float* __restrict__ acc1)
{
    int t = threadIdx.x;
    int wv = t >> 6, lane = t & 63;
    int p = lane & 15, q = lane >> 4;
    int i0 = blockIdx.x * 16;

    __shared__ float sh[16][129];
    __shared__ int stypes[16];
    if (t < 16) {
        int tt = sat[i0 + t];
        stypes[t] = min(max(tt, 0), NTYPES - 1);
    }

    // A fragments: row i0+p, k = s*32 + q*8 .. +7 (k-contiguous per lane)
    const ushortT* arow_m = mbf + (size_t)(i0 + p) * HH + q * 8;
    const ushortT* arow_h = hbf + (size_t)(i0 + p) * HH + q * 8;
    short8 am[4], ah[4];
    #pragma unroll
    for (int s = 0; s < 4; ++s) {
        am[s] = *(const short8*)(arow_m + s * 32);
        ah[s] = *(const short8*)(arow_h + s * 32);
    }

    #pragma unroll
    for (int nt = 0; nt < 2; ++nt) {
        int n0 = (wv * 2 + nt) * 16;
        const ushortT* brow_l = Wlbf + (size_t)(n0 + p) * HH + q * 8;
        const ushortT* brow_r = Wrbf + (size_t)(n0 + p) * HH + q * 8;
        f32x4 acc = {0.f, 0.f, 0.f, 0.f};
        #pragma unroll
        for (int s = 0; s < 4; ++s) {
            short8 b = *(const short8*)(brow_l + s * 32);
            acc = __builtin_amdgcn_mfma_f32_16x16x32_bf16(am[s], b, acc, 0, 0, 0);
        }
        #pragma unroll
        for (int s = 0; s < 4; ++s) {
            short8 b = *(const short8*)(brow_r + s * 32);
            acc = __builtin_amdgcn_mfma_f32_16x16x32_bf16(ah[s], b, acc, 0, 0, 0);
        }
        int o = n0 + p;              // D col = lane&15
        float bv = bl[o];
        #pragma unroll
        for (int rg = 0; rg < 4; ++rg) {
            float v = fmaxf(acc[rg] + bv, 0.f);
            sh[q * 4 + rg][o] = v;   // D row = quad*4 + reg
        }
    }
    __syncthreads();

    // coalesced writes
    #pragma unroll
    for (int e = 0; e < 8; ++e) {
        int lin = e * 256 + t;
        int rr = lin >> 7, cc = lin & 127;
        float v = sh[rr][cc];
        hout[(size_t)i0 * HH + lin] = v;
        if (MODE == 1) houtbf[(size_t)i0 * HH + lin] = f2bf(v);
    }
    int rep = blockIdx.x & (NREP - 1);
    if (t < HH) {
        if (MODE == 1) {
            float accq[NTYPES] = {0.f, 0.f, 0.f, 0.f, 0.f, 0.f};
            for (int r = 0; r < 16; ++r) {
                float v = sh[r][t];
                int tt = stypes[r];
                #pragma unroll
                for (int qq = 0; qq < NTYPES; ++qq)
                    accq[qq] += (tt == qq) ? v : 0.f;
            }
            #pragma unroll
            for (int qq = 0; qq < NTYPES; ++qq)
                atomicAdd(&acc0[(rep * NTYPES + qq) * HH + t], accq[qq]);
        } else {
            float s = 0.f, s2 = 0.f;
            for (int r = 0; r < 16; ++r) {
                float v = sh[r][t];
                s += v; s2 += v * v;
            }
            atomicAdd(&acc0[rep * HH + t], s);
            atomicAdd(&acc1[rep * HH + t], s2);
        }
    }
}

// ---------------------------------------------------------------------------
// Kernel F: BN apply + head, one wave per row; sums the NREP stat replicas.
// ---------------------------------------------------------------------------
__global__ __launch_bounds__(256) void finalize(
    const float* __restrict__ h, const float* __restrict__ musum8,
    const float* __restrict__ varsum8, const float* __restrict__ gamma,
    const float* __restrict__ beta, const float* __restrict__ Wo,
    const float* __restrict__ bo, float* __restrict__ out_h,
    float* __restrict__ out_o)
{
    int t = threadIdx.x;
    int wv = t >> 6;
    int lane = t & 63;
    int i = blockIdx.x * 4 + wv;

    float2 mus = {0.f, 0.f}, vas = {0.f, 0.f};
    #pragma unroll
    for (int r = 0; r < NREP; ++r) {
        float2 a = ((const float2*)(musum8 + r * HH))[lane];
        float2 b = ((const float2*)(varsum8 + r * HH))[lane];
        mus.x += a.x; mus.y += a.y;
        vas.x += b.x; vas.y += b.y;
    }
    float2 ga  = ((const float2*)gamma)[lane];
    float2 be  = ((const float2*)beta)[lane];
    float mu0 = mus.x * (1.f / NN), mu1 = mus.y * (1.f / NN);
    float v0 = vas.x * (1.f / NN) - mu0 * mu0;
    float v1 = vas.y * (1.f / NN) - mu1 * mu1;
    float sc0 = ga.x / sqrtf(v0 + BN_EPS), sc1 = ga.y / sqrtf(v1 + BN_EPS);
    float sh0 = be.x - mu0 * sc0, sh1 = be.y - mu1 * sc1;

    float2 hv = ((const float2*)(h + (size_t)i * HH))[lane];
    float2 hb;
    hb.x = hv.x * sc0 + sh0;
    hb.y = hv.y * sc1 + sh1;
    ((float2*)(out_h + (size_t)i * HH))[lane] = hb;

    float2 w0 = ((const float2*)Wo)[lane];
    float2 w1 = ((const float2*)(Wo + HH))[lane];
    float2 w2 = ((const float2*)(Wo + 2 * HH))[lane];
    float p0 = hb.x * w0.x + hb.y * w0.y;
    float p1 = hb.x * w1.x + hb.y * w1.y;
    float p2 = hb.x * w2.x + hb.y * w2.y;
    for (int s = 32; s; s >>= 1) {
        p0 += __shfl_down(p0, s);
        p1 += __shfl_down(p1, s);
        p2 += __shfl_down(p2, s);
    }
    if (lane == 0) {
        out_o[(size_t)i * OUTD + 0] = p0 + bo[0];
        out_o[(size_t)i * OUTD + 1] = p1 + bo[1];
        out_o[(size_t)i * OUTD + 2] = p2 + bo[2];
    }
}

// ---------------------------------------------------------------------------
extern "C" void kernel_launch(void* const* d_in, const int* in_sizes, int n_in,
                              void* d_out, int out_size, void* d_ws, size_t ws_size,
                              hipStream_t stream)
{
    (void)in_sizes; (void)n_in; (void)out_size; (void)ws_size;
    const float* x_now = (const float*)d_in[0];
    const int*   sat   = (const int*)d_in[1];
    const float* Wl    = (const float*)d_in[2];
    const float* bl    = (const float*)d_in[3];
    const float* Wr    = (const float*)d_in[4];
    const float* gamma = (const float*)d_in[5];
    const float* beta  = (const float*)d_in[6];
    const float* Wo    = (const float*)d_in[7];
    const float* bo    = (const float*)d_in[8];

    float* ws = (float*)d_ws;
    float* x0 = ws;                               // 524288 f
    float* h1 = x0 + (size_t)NN * HH;             // 524288 f
    float* h2 = h1 + (size_t)NN * HH;             // 524288 f
    ushortT* Wbf  = (ushortT*)(h2 + (size_t)NN * HH);   // 65536 us [Wl0,Wl1,Wr0,Wr1]
    ushortT* x0bf = Wbf + 65536;                  // 524288 us
    ushortT* h1bf = x0bf + (size_t)NN * HH;       // 524288 us
    ushortT* mbf  = h1bf + (size_t)NN * HH;       // 524288 us (shared by both layers)
    float4* fn = (float4*)(mbf + (size_t)NN * HH);      // 4096 float4
    unsigned* mask = (unsigned*)((float*)fn + 4 * NN);  // 524288 words
    float* deg = (float*)(mask + (size_t)NN * 128);     // 4096
    // ---- zeroed accumulator region (one contiguous memset) ----
    int*   cnt   = (int*)(deg + NN);              // NREP*6 (reserve 64)
    float* S0rep = (float*)(cnt + 64);            // 6144
    float* S1rep = S0rep + NREP * NTYPES * HH;    // 6144
    float* mu8   = S1rep + NREP * NTYPES * HH;    // 1024
    float* var8  = mu8 + NREP * HH;               // 1024

    size_t zero_bytes = (64 + 2 * NREP * NTYPES * HH + 2 * NREP * HH)
                        * sizeof(float);
    hipMemsetAsync(cnt, 0, zero_bytes, stream);

    prep<<<264, 256, 0, stream>>>(x_now, sat, Wl, Wr, Wbf, x0, x0bf, fn, cnt,
                                  S0rep);
    build_mask<<<NN / MROW, 256, 0, stream>>>(fn, sat, cnt, mask, deg);

    // layer 1
    gather_kernel<<<NN / 2, 256, 0, stream>>>(x0, x0bf, mask, deg, S0rep, sat,
                                              mbf);
    gemm_kernel<1><<<NN / 16, 256, 0, stream>>>(
        mbf, x0bf, Wbf, Wbf + 32768, bl, sat, h1, h1bf, S1rep, nullptr);

    // layer 2
    gather_kernel<<<NN / 2, 256, 0, stream>>>(h1, h1bf, mask, deg, S1rep, sat,
                                              mbf);
    gemm_kernel<2><<<NN / 16, 256, 0, stream>>>(
        mbf, h1bf, Wbf + 16384, Wbf + 49152, bl + HH, sat, h2, nullptr,
        mu8, var8);

    finalize<<<NN / 4, 256, 0, stream>>>(h2, mu8, var8, gamma, beta, Wo, bo,
                                         (float*)d_out, (float*)d_out + (size_t)NN * HH);
}